// Round 12
// baseline (216.003 us; speedup 1.0000x reference)
//
#include <hip/hip_runtime.h>
#include <math.h>

#define DEV __device__ __forceinline__

constexpr int N_TRAIN = 131072;
constexpr int M_TEST  = 65536;
constexpr int T_TOT   = N_TRAIN + M_TEST;  // 196608
constexpr int TPB     = 64;                // single-wave blocks
constexpr int NBLK    = T_TOT / TPB;       // 3072 level-1 blocks
constexpr int MIDT    = 768;               // mid kernels: one block, 12 waves
constexpr int BPT     = NBLK / MIDT;       // 4 blocks per mid thread
constexpr int FE_S    = 33;                // FE record size (floats)

// ---------------- 3x3 helpers (row-major float[9]) ----------------
DEV void mm(const float* X, const float* Y, float* Z) {
#pragma unroll
  for (int i = 0; i < 3; ++i)
#pragma unroll
    for (int j = 0; j < 3; ++j)
      Z[i*3+j] = X[i*3]*Y[j] + X[i*3+1]*Y[3+j] + X[i*3+2]*Y[6+j];
}
DEV void mmnt(const float* X, const float* Y, float* Z) { // X * Y^T
#pragma unroll
  for (int i = 0; i < 3; ++i)
#pragma unroll
    for (int j = 0; j < 3; ++j)
      Z[i*3+j] = X[i*3]*Y[j*3] + X[i*3+1]*Y[j*3+1] + X[i*3+2]*Y[j*3+2];
}
DEV void mtn(const float* X, const float* Y, float* Z) { // X^T * Y
#pragma unroll
  for (int i = 0; i < 3; ++i)
#pragma unroll
    for (int j = 0; j < 3; ++j)
      Z[i*3+j] = X[i]*Y[j] + X[3+i]*Y[3+j] + X[6+i]*Y[6+j];
}
DEV void mv(const float* X, const float* v, float* w) {
#pragma unroll
  for (int i = 0; i < 3; ++i) w[i] = X[i*3]*v[0] + X[i*3+1]*v[1] + X[i*3+2]*v[2];
}
DEV void mtv(const float* X, const float* v, float* w) {
#pragma unroll
  for (int i = 0; i < 3; ++i) w[i] = X[i]*v[0] + X[3+i]*v[1] + X[6+i]*v[2];
}
// fp32 inverse — used for Mx = I + C*J (det>=1, well-conditioned)
DEV void inv3f(const float* m, float* o) {
  float c00 = m[4]*m[8] - m[5]*m[7];
  float c10 = m[5]*m[6] - m[3]*m[8];
  float c20 = m[3]*m[7] - m[4]*m[6];
  float det = m[0]*c00 + m[1]*c10 + m[2]*c20;
  float id = 1.0f / det;
  o[0] = c00*id; o[1] = (m[2]*m[7]-m[1]*m[8])*id; o[2] = (m[1]*m[5]-m[2]*m[4])*id;
  o[3] = c10*id; o[4] = (m[0]*m[8]-m[2]*m[6])*id; o[5] = (m[2]*m[3]-m[0]*m[5])*id;
  o[6] = c20*id; o[7] = (m[1]*m[6]-m[0]*m[7])*id; o[8] = (m[0]*m[4]-m[1]*m[3])*id;
}
// double-cofactor inverse — used for Pp^-1 (cond ~1e6+, cancellation hedge)
DEV void inv3d(const float* mf_, float* o) {
  double m0=mf_[0], m1=mf_[1], m2=mf_[2], m3=mf_[3], m4=mf_[4],
         m5=mf_[5], m6=mf_[6], m7=mf_[7], m8=mf_[8];
  double c00 = m4*m8 - m5*m7;
  double c10 = m5*m6 - m3*m8;
  double c20 = m3*m7 - m4*m6;
  double det = m0*c00 + m1*c10 + m2*c20;
  double id = 1.0 / det;
  o[0] = (float)(c00*id); o[1] = (float)((m2*m7-m1*m8)*id); o[2] = (float)((m1*m5-m2*m4)*id);
  o[3] = (float)(c10*id); o[4] = (float)((m0*m8-m2*m6)*id); o[5] = (float)((m2*m3-m0*m5)*id);
  o[6] = (float)(c20*id); o[7] = (float)((m1*m6-m0*m7)*id); o[8] = (float)((m0*m4-m1*m3)*id);
}
DEV void symm(float* P) {
  float a = 0.5f*(P[1]+P[3]), b = 0.5f*(P[2]+P[6]), c = 0.5f*(P[5]+P[7]);
  P[1]=P[3]=a; P[2]=P[6]=b; P[5]=P[7]=c;
}
// packed state (m, Psym) <-> 9 floats
DEV void st_state(const float* m, const float* P, float* g) {
  g[0]=m[0]; g[1]=m[1]; g[2]=m[2];
  g[3]=P[0]; g[4]=P[1]; g[5]=P[2]; g[6]=P[4]; g[7]=P[5]; g[8]=P[8];
}
DEV void ld_state(const float* g, float* m, float* P) {
  m[0]=g[0]; m[1]=g[1]; m[2]=g[2];
  P[0]=g[3]; P[1]=g[4]; P[2]=g[5];
  P[3]=g[4]; P[4]=g[6]; P[5]=g[7];
  P[6]=g[5]; P[7]=g[7]; P[8]=g[8];
}

// ---------------- model ----------------
struct Model { float lam, v, kap, l4; };
DEV Model make_model(const float* varp, const float* ellp) {
  Model M; M.v = varp[0];
  float ell = ellp[0];
  M.lam = sqrtf(5.0f) / ell;
  M.kap = M.lam * M.lam / 3.0f;
  float l2 = M.lam * M.lam;
  M.l4 = l2 * l2;
  return M;
}
DEV void pinf(const Model& M, float* P) {
  float vk = M.v * M.kap;
  P[0]=M.v; P[1]=0;  P[2]=-vk;
  P[3]=0;   P[4]=vk; P[5]=0;
  P[6]=-vk; P[7]=0;  P[8]=M.v*M.l4;
}
DEV void make_AQ(const Model& M, float dt, float* A, float* Q) {
  float lam = M.lam, l2 = lam*lam, l3 = l2*lam, l4 = M.l4;
  float e = __expf(-lam * dt);
  float h = 0.5f * dt * dt;
  A[0] = e*(1.0f + dt*lam + h*l2);
  A[1] = e*(dt + 2.0f*h*lam);
  A[2] = e*h;
  A[3] = e*(-h*l3);
  A[4] = e*(1.0f + dt*lam - 2.0f*h*l2);
  A[5] = e*(dt - h*lam);
  A[6] = e*(-dt*l3 + h*l4);
  A[7] = e*(-3.0f*dt*l2 + 2.0f*h*l3);
  A[8] = e*(1.0f - 2.0f*dt*lam + h*l2);
  float vk = M.v * M.kap, vl4 = M.v * M.l4;
  float B[9];  // A * Pinf
#pragma unroll
  for (int i = 0; i < 3; ++i) {
    B[i*3+0] =  A[i*3+0]*M.v - A[i*3+2]*vk;
    B[i*3+1] =  A[i*3+1]*vk;
    B[i*3+2] = -A[i*3+0]*vk  + A[i*3+2]*vl4;
  }
  float Pi[9]; pinf(M, Pi);
#pragma unroll
  for (int i = 0; i < 3; ++i)
#pragma unroll
    for (int j = 0; j < 3; ++j)
      Q[i*3+j] = Pi[i*3+j] - (B[i*3]*A[j*3] + B[i*3+1]*A[j*3+1] + B[i*3+2]*A[j*3+2]);
}

// ---------------- filter scan element ----------------
struct FE { float A[9]; float b[3]; float C[9]; float h[3]; float J[9]; };

DEV FE fe_identity() {
  FE e;
#pragma unroll
  for (int i=0;i<9;++i){ e.A[i]=0.0f; e.C[i]=0.0f; e.J[i]=0.0f; }
  e.A[0]=e.A[4]=e.A[8]=1.0f;
  e.b[0]=e.b[1]=e.b[2]=0.0f; e.h[0]=e.h[1]=e.h[2]=0.0f;
  return e;
}
DEV void fe_store(const FE& e, float* g) {          // contiguous 33 (LDS)
#pragma unroll
  for (int i=0;i<9;++i) g[i]=e.A[i];
  g[9]=e.b[0]; g[10]=e.b[1]; g[11]=e.b[2];
#pragma unroll
  for (int i=0;i<9;++i) g[12+i]=e.C[i];
  g[21]=e.h[0]; g[22]=e.h[1]; g[23]=e.h[2];
#pragma unroll
  for (int i=0;i<9;++i) g[24+i]=e.J[i];
}
DEV FE fe_load(const float* g) {
  FE e;
#pragma unroll
  for (int i=0;i<9;++i) e.A[i]=g[i];
  e.b[0]=g[9]; e.b[1]=g[10]; e.b[2]=g[11];
#pragma unroll
  for (int i=0;i<9;++i) e.C[i]=g[12+i];
  e.h[0]=g[21]; e.h[1]=g[22]; e.h[2]=g[23];
#pragma unroll
  for (int i=0;i<9;++i) e.J[i]=g[24+i];
  return e;
}
// transposed (component-major) global layout: g[comp*n + idx] -> lane-coalesced
DEV void fe_storeT(const FE& e, float* g, int idx, int n) {
#pragma unroll
  for (int i=0;i<9;++i) g[i*n+idx]=e.A[i];
#pragma unroll
  for (int i=0;i<3;++i) g[(9+i)*n+idx]=e.b[i];
#pragma unroll
  for (int i=0;i<9;++i) g[(12+i)*n+idx]=e.C[i];
#pragma unroll
  for (int i=0;i<3;++i) g[(21+i)*n+idx]=e.h[i];
#pragma unroll
  for (int i=0;i<9;++i) g[(24+i)*n+idx]=e.J[i];
}
DEV FE fe_loadT(const float* g, int idx, int n) {
  FE e;
#pragma unroll
  for (int i=0;i<9;++i) e.A[i]=g[i*n+idx];
#pragma unroll
  for (int i=0;i<3;++i) e.b[i]=g[(9+i)*n+idx];
#pragma unroll
  for (int i=0;i<9;++i) e.C[i]=g[(12+i)*n+idx];
#pragma unroll
  for (int i=0;i<3;++i) e.h[i]=g[(21+i)*n+idx];
#pragma unroll
  for (int i=0;i<9;++i) e.J[i]=g[(24+i)*n+idx];
  return e;
}
// load (b,C) of a prefix element as a state (valid when prefix includes elem 0)
DEV void fe_loadT_state(const float* g, int idx, int n, float* m, float* P) {
#pragma unroll
  for (int i=0;i<3;++i) m[i]=g[(9+i)*n+idx];
#pragma unroll
  for (int i=0;i<9;++i) P[i]=g[(12+i)*n+idx];
}
DEV FE fe_shfl_up(const FE& e, int d) {
  FE o;
#pragma unroll
  for (int i=0;i<9;++i) o.A[i]=__shfl_up(e.A[i], d, 64);
#pragma unroll
  for (int i=0;i<3;++i) o.b[i]=__shfl_up(e.b[i], d, 64);
#pragma unroll
  for (int i=0;i<9;++i) o.C[i]=__shfl_up(e.C[i], d, 64);
#pragma unroll
  for (int i=0;i<3;++i) o.h[i]=__shfl_up(e.h[i], d, 64);
#pragma unroll
  for (int i=0;i<9;++i) o.J[i]=__shfl_up(e.J[i], d, 64);
  return o;
}
DEV FE build_felem(const Model& M, float dt, float obsf, float rf, float Rf_, bool first) {
  FE E;
  float r = rf, R = Rf_;
  float g = (obsf > 0.5f) ? 1.0f : 0.0f;
  if (first) {
#pragma unroll
    for (int i=0;i<9;++i){ E.A[i]=0.0f; E.J[i]=0.0f; }
    E.h[0]=E.h[1]=E.h[2]=0.0f;
    float Pi[9]; pinf(M, Pi);
    float S = Pi[0] + R;
    float f = g / S;
    float K0=Pi[0]*f, K1=Pi[3]*f, K2=Pi[6]*f;
    E.b[0]=K0*r; E.b[1]=K1*r; E.b[2]=K2*r;
    E.C[0]=Pi[0]-S*K0*K0; E.C[1]=Pi[1]-S*K0*K1; E.C[2]=Pi[2]-S*K0*K2;
    E.C[3]=Pi[3]-S*K1*K0; E.C[4]=Pi[4]-S*K1*K1; E.C[5]=Pi[5]-S*K1*K2;
    E.C[6]=Pi[6]-S*K2*K0; E.C[7]=Pi[7]-S*K2*K1; E.C[8]=Pi[8]-S*K2*K2;
    return E;
  }
  float Am[9], Q[9]; make_AQ(M, dt, Am, Q);
  float S = Q[0] + R, iS = g / S;   // gated: obs=0 -> K=0, A=Am, C=Q, h=0, J=0
  float K0=Q[0]*iS, K1=Q[3]*iS, K2=Q[6]*iS;
#pragma unroll
  for (int j = 0; j < 3; ++j) {
    E.A[j]   = Am[j]   - K0*Am[j];
    E.A[3+j] = Am[3+j] - K1*Am[j];
    E.A[6+j] = Am[6+j] - K2*Am[j];
    E.C[j]   = Q[j]    - K0*Q[j];
    E.C[3+j] = Q[3+j]  - K1*Q[j];
    E.C[6+j] = Q[6+j]  - K2*Q[j];
  }
  E.b[0]=K0*r; E.b[1]=K1*r; E.b[2]=K2*r;
  float riS = r*iS;
  E.h[0]=Am[0]*riS; E.h[1]=Am[1]*riS; E.h[2]=Am[2]*riS;
#pragma unroll
  for (int i = 0; i < 3; ++i)
#pragma unroll
    for (int j = 0; j < 3; ++j)
      E.J[i*3+j] = Am[i]*Am[j]*iS;
  return E;
}
// compose: x earlier, y later
DEV FE fcompose(const FE& x, const FE& y) {
  const float *A1=x.A,*b1=x.b,*C1=x.C,*h1=x.h,*J1=x.J;
  const float *A2=y.A,*b2=y.b,*C2=y.C,*h2=y.h,*J2=y.J;
  FE o;
  float Mx[9]; mm(C1,J2,Mx); Mx[0]+=1.0f; Mx[4]+=1.0f; Mx[8]+=1.0f;
  float Mi[9]; inv3f(Mx,Mi);
  float T1[9]; mm(A2,Mi,T1);
  mm(T1,A1,o.A);
  float u[3]; mv(C1,h2,u); u[0]+=b1[0]; u[1]+=b1[1]; u[2]+=b1[2];
  mv(T1,u,o.b); o.b[0]+=b2[0]; o.b[1]+=b2[1]; o.b[2]+=b2[2];
  float t2[9]; mm(T1,C1,t2);
  mmnt(t2,A2,o.C);
#pragma unroll
  for (int i=0;i<9;++i) o.C[i]+=C2[i];
  float tmp[9]; mm(Mi,A1,tmp);
  float w[3]; mv(J2,b1,w);
  w[0]=h2[0]-w[0]; w[1]=h2[1]-w[1]; w[2]=h2[2]-w[2];
  mtv(tmp,w,o.h); o.h[0]+=h1[0]; o.h[1]+=h1[1]; o.h[2]+=h1[2];
  float V[9]; mm(J2,A1,V);
  mtn(tmp,V,o.J);
#pragma unroll
  for (int i=0;i<9;++i) o.J[i]+=J1[i];
  symm(o.C); symm(o.J);
  return o;
}
// apply element y (later) to a state (m,P): reduced compose (A1=0,h1=0,J1=0)
DEV void fapply(const FE& y, float* m, float* P) {
  float Mx[9]; mm(P, y.J, Mx); Mx[0]+=1.0f; Mx[4]+=1.0f; Mx[8]+=1.0f;
  float Mi[9]; inv3f(Mx, Mi);
  float T1[9]; mm(y.A, Mi, T1);
  float u[3]; mv(P, y.h, u); u[0]+=m[0]; u[1]+=m[1]; u[2]+=m[2];
  float mn[3]; mv(T1, u, mn);
  m[0]=mn[0]+y.b[0]; m[1]=mn[1]+y.b[1]; m[2]=mn[2]+y.b[2];
  float t2[9]; mm(T1, P, t2);
  float Pn[9]; mmnt(t2, y.A, Pn);
#pragma unroll
  for (int i=0;i<9;++i) P[i]=Pn[i]+y.C[i];
  symm(P);
}
// plain Kalman step (replay)
DEV void fstep(const Model& M, float dt, float obsf, float rf, float Rf_,
               float* m, float* P) {
  float A[9], Q[9]; make_AQ(M, dt, A, Q);
  float mp[3]; mv(A, m, mp);
  float W[9]; mmnt(P, A, W);      // P A^T
  float Pp[9]; mm(A, W, Pp);
#pragma unroll
  for (int i=0;i<9;++i) Pp[i]+=Q[i];
  float S = Pp[0] + Rf_;
  float f = (obsf > 0.5f) ? (1.0f/S) : 0.0f;
  float K0=Pp[0]*f, K1=Pp[3]*f, K2=Pp[6]*f;
  float v = rf - mp[0];
  m[0]=mp[0]+K0*v; m[1]=mp[1]+K1*v; m[2]=mp[2]+K2*v;
  P[0]=Pp[0]-S*K0*K0; P[1]=Pp[1]-S*K0*K1; P[2]=Pp[2]-S*K0*K2;
  P[3]=Pp[3]-S*K1*K0; P[4]=Pp[4]-S*K1*K1; P[5]=Pp[5]-S*K1*K2;
  P[6]=Pp[6]-S*K2*K0; P[7]=Pp[7]-S*K2*K1; P[8]=Pp[8]-S*K2*K2;
  symm(P);
}

// ---------------- smoother affine map: x_k = G x_{k+1} + c ; P_k = G P G^T + U ----------------
struct SE { float G[9]; float c[3]; float U[9]; };

DEV SE se_identity() {
  SE s;
#pragma unroll
  for (int i=0;i<9;++i){ s.G[i]=0.0f; s.U[i]=0.0f; }
  s.G[0]=s.G[4]=s.G[8]=1.0f;
  s.c[0]=s.c[1]=s.c[2]=0.0f;
  return s;
}
DEV void se_store(const SE& s, float* g) {   // contiguous packed-18 (LDS)
#pragma unroll
  for (int i=0;i<9;++i) g[i]=s.G[i];
  g[9]=s.c[0]; g[10]=s.c[1]; g[11]=s.c[2];
  g[12]=s.U[0]; g[13]=s.U[1]; g[14]=s.U[2]; g[15]=s.U[4]; g[16]=s.U[5]; g[17]=s.U[8];
}
DEV SE se_load(const float* g) {
  SE s;
#pragma unroll
  for (int i=0;i<9;++i) s.G[i]=g[i];
  s.c[0]=g[9]; s.c[1]=g[10]; s.c[2]=g[11];
  s.U[0]=g[12]; s.U[1]=g[13]; s.U[2]=g[14];
  s.U[3]=g[13]; s.U[4]=g[15]; s.U[5]=g[16];
  s.U[6]=g[14]; s.U[7]=g[16]; s.U[8]=g[17];
  return s;
}
DEV void se_storeT(const SE& s, float* g, int idx, int n) {  // component-major
#pragma unroll
  for (int i=0;i<9;++i) g[i*n+idx]=s.G[i];
#pragma unroll
  for (int i=0;i<3;++i) g[(9+i)*n+idx]=s.c[i];
  g[12*n+idx]=s.U[0]; g[13*n+idx]=s.U[1]; g[14*n+idx]=s.U[2];
  g[15*n+idx]=s.U[4]; g[16*n+idx]=s.U[5]; g[17*n+idx]=s.U[8];
}
DEV SE se_loadT(const float* g, int idx, int n) {
  SE s;
#pragma unroll
  for (int i=0;i<9;++i) s.G[i]=g[i*n+idx];
#pragma unroll
  for (int i=0;i<3;++i) s.c[i]=g[(9+i)*n+idx];
  float u0=g[12*n+idx], u1=g[13*n+idx], u2=g[14*n+idx],
        u4=g[15*n+idx], u5=g[16*n+idx], u8=g[17*n+idx];
  s.U[0]=u0; s.U[1]=u1; s.U[2]=u2;
  s.U[3]=u1; s.U[4]=u4; s.U[5]=u5;
  s.U[6]=u2; s.U[7]=u5; s.U[8]=u8;
  return s;
}
DEV SE se_shfl_down(const SE& s, int d) {
  SE o;
#pragma unroll
  for (int i=0;i<9;++i) o.G[i]=__shfl_down(s.G[i], d, 64);
#pragma unroll
  for (int i=0;i<3;++i) o.c[i]=__shfl_down(s.c[i], d, 64);
#pragma unroll
  for (int i=0;i<9;++i) o.U[i]=__shfl_down(s.U[i], d, 64);
  return o;
}
// x earlier in time (applied LAST, since smoother runs backward)
DEV SE scompose(const SE& x, const SE& y) {
  SE o;
  mm(x.G, y.G, o.G);
  float t[3]; mv(x.G, y.c, t);
  o.c[0]=t[0]+x.c[0]; o.c[1]=t[1]+x.c[1]; o.c[2]=t[2]+x.c[2];
  float T[9]; mm(x.G, y.U, T);
  mmnt(T, x.G, o.U);
#pragma unroll
  for (int i=0;i<9;++i) o.U[i]+=x.U[i];
  symm(o.U);
  return o;
}
DEV void sapply(const SE& s, float* m, float* P) {
  float t[3]; mv(s.G, m, t);
  float T[9]; mm(s.G, P, T);
  float Pn[9]; mmnt(T, s.G, Pn);
  m[0]=t[0]+s.c[0]; m[1]=t[1]+s.c[1]; m[2]=t[2]+s.c[2];
#pragma unroll
  for (int i=0;i<9;++i) P[i]=Pn[i]+s.U[i];
  symm(P);
}
// smoother element from filtered register state (m,P) at k, dt to k+1
DEV SE selem_from_state(const Model& M, const float* m, const float* P, float dtn) {
  SE s;
  float A[9], Q[9]; make_AQ(M, dtn, A, Q);
  float W[9]; mmnt(P, A, W);      // P A^T
  float Pp[9]; mm(A, W, Pp);
#pragma unroll
  for (int j=0;j<9;++j) Pp[j]+=Q[j];
  float Pi_[9]; inv3d(Pp, Pi_);    // ill-conditioned -> double cofactors
  mm(W, Pi_, s.G);                 // G = P A^T Pp^-1
  float mp[3]; mv(A, m, mp);
  float gm[3]; mv(s.G, mp, gm);
  s.c[0]=m[0]-gm[0]; s.c[1]=m[1]-gm[1]; s.c[2]=m[2]-gm[2];
  float GW[9]; mmnt(s.G, W, GW);   // G Pp G^T
#pragma unroll
  for (int j=0;j<9;++j) s.U[j]=P[j]-GW[j];
  symm(s.U);
  return s;
}

// ================= kernels =================
// pk[k] = {time, residual, R, is_obs}  (natural order)
__global__ void k_merge(const float* __restrict__ times, const float* __restrict__ tstar,
                        const float* __restrict__ n1, const float* __restrict__ n2,
                        const float* __restrict__ mcp,
                        float4* pk, int* oix) {
  int g = blockIdx.x*blockDim.x + threadIdx.x;
  if (g >= T_TOT) return;
  float mc = mcp[0];
  if (g < N_TRAIN) {
    int i = g;
    float t = times[i];
    int lo = 0, hi = M_TEST;                 // count tstar strictly < t
    while (lo < hi) { int mid=(lo+hi)>>1; if (tstar[mid] < t) lo=mid+1; else hi=mid; }
    int p = i + lo;
    float s2 = n2[i];
    pk[p] = make_float4(t, n1[i]/s2 - mc, 1.0f/s2, 1.0f);
    oix[p] = -1;
  } else {
    int j = g - N_TRAIN;
    float t = tstar[j];
    int lo = 0, hi = N_TRAIN;                // count times <= t (stable: train first)
    while (lo < hi) { int mid=(lo+hi)>>1; if (times[mid] <= t) lo=mid+1; else hi=mid; }
    int p = j + lo;
    pk[p] = make_float4(t, 0.f, 1.f, 0.f);
    oix[p] = j;
  }
}

// F1: one element per thread, 64-wide shuffle inclusive scan.
__global__ __launch_bounds__(TPB, 3) void k_f1(
    const float* varp, const float* ellp, const float4* __restrict__ pk,
    float* tIncl, float* blkAgg) {
  int l = threadIdx.x, b = blockIdx.x;
  int t = b*TPB + l;
  Model M = make_model(varp, ellp);
  float4 q = pk[t];
  float dt = (t == 0) ? 0.0f : (q.x - pk[t-1].x);
  FE run = build_felem(M, dt, q.w, q.y, q.z, t == 0);
  for (int d = 1; d < TPB; d <<= 1) {
    FE oth = fe_shfl_up(run, d);
    FE comp = fcompose(oth, run);
    if (l >= d) run = comp;
  }
  fe_storeT(run, tIncl, t, T_TOT);
  if (l == TPB-1) fe_storeT(run, blkAgg, b, NBLK);
}

// FMID: one 768-thread block (12 waves) scans all 3072 block aggregates and
// emits per-block ENTRY STATES blkPref[b] (9 floats; b>=1; prefix contains elem 0).
__global__ __launch_bounds__(MIDT) void k_fmid(const float* __restrict__ blkAgg,
                                               float* blkPref) {
  __shared__ float lds[12*FE_S];
  int j = threadIdx.x, w = j >> 6, l = j & 63;
  // serial compose of 4 consecutive block aggregates (reload later, keep regs low)
  FE A = fe_loadT(blkAgg, 4*j+0, NBLK);
  A = fcompose(A, fe_loadT(blkAgg, 4*j+1, NBLK));
  A = fcompose(A, fe_loadT(blkAgg, 4*j+2, NBLK));
  A = fcompose(A, fe_loadT(blkAgg, 4*j+3, NBLK));
  // in-wave inclusive scan
  FE I = A;
  for (int d = 1; d < 64; d <<= 1) {
    FE oth = fe_shfl_up(I, d);
    FE c = fcompose(oth, I);
    if (l >= d) I = c;
  }
  if (l == 63) fe_store(I, &lds[w*FE_S]);
  __syncthreads();
  if (w == 0) {  // lanes 0..11 hold wave aggregates; scan; write EXCLUSIVE prefixes
    FE Wg = (l < 12) ? fe_load(&lds[l*FE_S]) : fe_identity();
    for (int d = 1; d < 16; d <<= 1) {
      FE oth = fe_shfl_up(Wg, d);
      FE c = fcompose(oth, Wg);
      if (l >= d) Wg = c;
    }
    FE X = fe_shfl_up(Wg, 1);
    if (l >= 1 && l < 12) fe_store(X, &lds[l*FE_S]);  // slot w = prefix over waves < w
  }
  __syncthreads();
  // state before this thread's first block
  float m[3], P[9];
  bool have = false;
  FE Ix = fe_shfl_up(I, 1);     // in-wave exclusive (valid l>=1)
  if (w == 0) {
    if (l > 0) {
      m[0]=Ix.b[0]; m[1]=Ix.b[1]; m[2]=Ix.b[2];
#pragma unroll
      for (int i=0;i<9;++i) P[i]=Ix.C[i];
      have = true;
    }
  } else {
    const float* wp = &lds[w*FE_S];   // state (contains elem 0)
    m[0]=wp[9]; m[1]=wp[10]; m[2]=wp[11];
#pragma unroll
    for (int i=0;i<9;++i) P[i]=wp[12+i];
    have = true;
    if (l > 0) fapply(Ix, m, P);
  }
  int b0 = 4*j;
  if (have) st_state(m, P, blkPref + (size_t)b0*9);
  {
    FE a = fe_loadT(blkAgg, b0+0, NBLK);
    if (!have) {
      m[0]=a.b[0]; m[1]=a.b[1]; m[2]=a.b[2];
#pragma unroll
      for (int i=0;i<9;++i) P[i]=a.C[i];
      have = true;
    } else fapply(a, m, P);
    st_state(m, P, blkPref + (size_t)(b0+1)*9);
  }
  { FE a = fe_loadT(blkAgg, b0+1, NBLK); fapply(a, m, P); st_state(m, P, blkPref + (size_t)(b0+2)*9); }
  { FE a = fe_loadT(blkAgg, b0+2, NBLK); fapply(a, m, P); st_state(m, P, blkPref + (size_t)(b0+3)*9); }
}

// F3 (+fused s1): entry state + (<=1 fapply) + fstep + smoother element in regs +
// backward in-wave suffix scan; store row-0 data (5 floats) + lane0 block aggregate.
__global__ __launch_bounds__(TPB, 3) void k_f3(
    const float* varp, const float* ellp, const float4* __restrict__ pk,
    const float* __restrict__ tIncl, const float* __restrict__ blkPref,
    float* out5, float* blkAggS, float* xT) {
  int l = threadIdx.x, b = blockIdx.x;
  int t = b*TPB + l;
  Model M = make_model(varp, ellp);
  float m[3], P[9];
  if (t == 0) {
    m[0]=m[1]=m[2]=0.0f; pinf(M, P);
  } else if (b == 0) {                        // block 0: tIncl[t-1] is a state
    fe_loadT_state(tIncl, t-1, T_TOT, m, P);
  } else {
    ld_state(blkPref + (size_t)b*9, m, P);
    if (l > 0) { FE y = fe_loadT(tIncl, t-1, T_TOT); fapply(y, m, P); }
  }
  float4 q = pk[t];
  float dt = (t == 0) ? 0.0f : (q.x - pk[t-1].x);
  fstep(M, dt, q.w, q.y, q.z, m, P);
  SE e;
  if (t < T_TOT-1) {
    float dtn = pk[t+1].x - q.x;
    e = selem_from_state(M, m, P, dtn);
  } else {
    e = se_identity();
    xT[0]=m[0]; xT[1]=m[1]; xT[2]=m[2];
    xT[3]=P[0]; xT[4]=P[1]; xT[5]=P[2];
    xT[6]=P[4]; xT[7]=P[5]; xT[8]=P[8];
  }
  // backward in-wave suffix scan: Macc[l] = e_l ∘ ... ∘ e_63
  SE Macc = e;
  for (int d = 1; d < TPB; d <<= 1) {
    SE oth = se_shfl_down(Macc, d);
    SE c = scompose(Macc, oth);
    if (l + d < TPB) Macc = c;
  }
  // row-0 of the map is all s3 needs for (m0, P00)
  out5[0*T_TOT+t] = Macc.G[0];
  out5[1*T_TOT+t] = Macc.G[1];
  out5[2*T_TOT+t] = Macc.G[2];
  out5[3*T_TOT+t] = Macc.c[0];
  out5[4*T_TOT+t] = Macc.U[0];
  if (l == 0) se_storeT(Macc, blkAggS, b, NBLK);
}

// SMID: one 768-thread block backward-scans 3072 block aggregates; emits per-block
// EXIT STATES bExit[b] (9 floats) = suffix of blocks > b applied to xT.
__global__ __launch_bounds__(MIDT) void k_smid(const float* __restrict__ blkAggS,
                                               const float* __restrict__ xT,
                                               float* bExit) {
  __shared__ float lds[12*18];
  int j = threadIdx.x, w = j >> 6, l = j & 63;
  SE A = se_loadT(blkAggS, 4*j+0, NBLK);
  A = scompose(A, se_loadT(blkAggS, 4*j+1, NBLK));
  A = scompose(A, se_loadT(blkAggS, 4*j+2, NBLK));
  A = scompose(A, se_loadT(blkAggS, 4*j+3, NBLK));
  // in-wave inclusive suffix scan
  SE I = A;
  for (int d = 1; d < 64; d <<= 1) {
    SE oth = se_shfl_down(I, d);
    SE c = scompose(I, oth);
    if (l + d < 64) I = c;
  }
  if (l == 0) se_store(I, &lds[w*18]);
  __syncthreads();
  if (w == 0) {  // suffix-scan the 12 wave aggregates; write suffix-of-waves>w
    SE Wg = (l < 12) ? se_load(&lds[l*18]) : se_identity();
    for (int d = 1; d < 16; d <<= 1) {
      SE oth = se_shfl_down(Wg, d);
      SE c = scompose(Wg, oth);
      if (l + d < 64) Wg = c;
    }
    SE WS = se_shfl_down(Wg, 1);    // lane 11 pulls lane 12's identity -> identity
    if (l < 12) se_store(WS, &lds[l*18]);
  }
  __syncthreads();
  float m[3] = { xT[0], xT[1], xT[2] };
  float P[9] = { xT[3],xT[4],xT[5], xT[4],xT[6],xT[7], xT[5],xT[7],xT[8] };
  { SE WSw = se_load(&lds[w*18]); sapply(WSw, m, P); }       // waves > w (identity for w=11)
  { SE Tn = se_shfl_down(I, 1); if (l < 63) sapply(Tn, m, P); }  // lanes > l
  int b0 = 4*j;
  st_state(m, P, bExit + (size_t)(b0+3)*9);
  { SE s = se_loadT(blkAggS, b0+3, NBLK); sapply(s, m, P); st_state(m, P, bExit + (size_t)(b0+2)*9); }
  { SE s = se_loadT(blkAggS, b0+2, NBLK); sapply(s, m, P); st_state(m, P, bExit + (size_t)(b0+1)*9); }
  { SE s = se_loadT(blkAggS, b0+1, NBLK); sapply(s, m, P); st_state(m, P, bExit + (size_t)(b0+0)*9); }
}

// S3: trivial — x_t row-0 = row0(Macc[t]) applied to bExit[block(t)]; write output.
__global__ __launch_bounds__(256, 4) void k_s3(
    const float* mcp, const float* __restrict__ out5,
    const float* __restrict__ bExit,
    const int* __restrict__ oix, float* out) {
  int t = blockIdx.x*256 + threadIdx.x;
  int b = t >> 6;
  float mc = mcp[0];
  const float* ge = bExit + (size_t)b*9;
  float m0=ge[0], m1=ge[1], m2=ge[2];
  float p00=ge[3], p01=ge[4], p02=ge[5], p11=ge[6], p12=ge[7], p22=ge[8];
  float g0 = out5[0*T_TOT+t], g1 = out5[1*T_TOT+t], g2 = out5[2*T_TOT+t];
  float c0 = out5[3*T_TOT+t], u00 = out5[4*T_TOT+t];
  float mm0 = g0*m0 + g1*m1 + g2*m2 + c0;
  float q0 = g0*p00 + g1*p01 + g2*p02;
  float q1 = g0*p01 + g1*p11 + g2*p12;
  float q2 = g0*p02 + g1*p12 + g2*p22;
  float v00 = q0*g0 + q1*g1 + q2*g2 + u00;
  int j = oix[t];
  if (j >= 0) { out[j] = mm0 + mc; out[M_TEST + j] = fmaxf(v00, 0.0f); }
}

extern "C" void kernel_launch(void* const* d_in, const int* in_sizes, int n_in,
                              void* d_out, int out_size, void* d_ws, size_t ws_size,
                              hipStream_t stream) {
  const float* times = (const float*)d_in[0];
  const float* tstar = (const float*)d_in[1];
  const float* n1    = (const float*)d_in[2];
  const float* n2    = (const float*)d_in[3];
  const float* varp  = (const float*)d_in[4];
  const float* ellp  = (const float*)d_in[5];
  const float* mcp   = (const float*)d_in[6];
  float* out = (float*)d_out;

  size_t off = 0;
  auto take = [&](size_t bytes) {
    char* p = (char*)d_ws + off;
    off += (bytes + 255) & ~(size_t)255;
    return (void*)p;
  };
  float4* pk     = (float4*)take(sizeof(float4) * T_TOT);
  int*    oix    = (int*)   take(sizeof(int)    * T_TOT);
  float*  tIncl  = (float*) take(sizeof(float)  * FE_S * T_TOT);
  float*  blkAgg = (float*) take(sizeof(float)  * FE_S * NBLK);
  float*  blkPref= (float*) take(sizeof(float)  * 9  * NBLK);
  float*  out5   = (float*) take(sizeof(float)  * 5  * T_TOT);
  float*  blkAggS= (float*) take(sizeof(float)  * 18 * NBLK);
  float*  bExit  = (float*) take(sizeof(float)  * 9  * NBLK);
  float*  xT     = (float*) take(sizeof(float)  * 9);
  (void)ws_size; (void)in_sizes; (void)n_in; (void)out_size;

  k_merge<<<(T_TOT+255)/256, 256, 0, stream>>>(times, tstar, n1, n2, mcp, pk, oix);
  k_f1   <<<NBLK, TPB, 0, stream>>>(varp, ellp, pk, tIncl, blkAgg);
  k_fmid <<<1, MIDT, 0, stream>>>(blkAgg, blkPref);
  k_f3   <<<NBLK, TPB, 0, stream>>>(varp, ellp, pk, tIncl, blkPref, out5, blkAggS, xT);
  k_smid <<<1, MIDT, 0, stream>>>(blkAggS, xT, bExit);
  k_s3   <<<T_TOT/256, 256, 0, stream>>>(mcp, out5, bExit, oix, out);
}

// Round 13
// 143.906 us; speedup vs baseline: 1.5010x; 1.5010x over previous
//
#include <hip/hip_runtime.h>
#include <math.h>

#define DEV __device__ __forceinline__

constexpr int N_TRAIN = 131072;
constexpr int M_TEST  = 65536;
constexpr int T_TOT   = N_TRAIN + M_TEST;  // 196608
constexpr int TPB     = 64;                // single-wave blocks
constexpr int NBLK    = T_TOT / TPB;       // 3072 level-1 blocks
constexpr int GRP     = 64;                // blocks per group
constexpr int NGRP    = NBLK / GRP;        // 48 groups
constexpr int FE_S    = 33;                // FE record size (floats)

// ---------------- 3x3 helpers (row-major float[9]) ----------------
DEV void mm(const float* X, const float* Y, float* Z) {
#pragma unroll
  for (int i = 0; i < 3; ++i)
#pragma unroll
    for (int j = 0; j < 3; ++j)
      Z[i*3+j] = X[i*3]*Y[j] + X[i*3+1]*Y[3+j] + X[i*3+2]*Y[6+j];
}
DEV void mmnt(const float* X, const float* Y, float* Z) { // X * Y^T
#pragma unroll
  for (int i = 0; i < 3; ++i)
#pragma unroll
    for (int j = 0; j < 3; ++j)
      Z[i*3+j] = X[i*3]*Y[j*3] + X[i*3+1]*Y[j*3+1] + X[i*3+2]*Y[j*3+2];
}
DEV void mtn(const float* X, const float* Y, float* Z) { // X^T * Y
#pragma unroll
  for (int i = 0; i < 3; ++i)
#pragma unroll
    for (int j = 0; j < 3; ++j)
      Z[i*3+j] = X[i]*Y[j] + X[3+i]*Y[3+j] + X[6+i]*Y[6+j];
}
DEV void mv(const float* X, const float* v, float* w) {
#pragma unroll
  for (int i = 0; i < 3; ++i) w[i] = X[i*3]*v[0] + X[i*3+1]*v[1] + X[i*3+2]*v[2];
}
DEV void mtv(const float* X, const float* v, float* w) {
#pragma unroll
  for (int i = 0; i < 3; ++i) w[i] = X[i]*v[0] + X[3+i]*v[1] + X[6+i]*v[2];
}
// fp32 inverse — used for Mx = I + C*J (det>=1, well-conditioned)
DEV void inv3f(const float* m, float* o) {
  float c00 = m[4]*m[8] - m[5]*m[7];
  float c10 = m[5]*m[6] - m[3]*m[8];
  float c20 = m[3]*m[7] - m[4]*m[6];
  float det = m[0]*c00 + m[1]*c10 + m[2]*c20;
  float id = 1.0f / det;
  o[0] = c00*id; o[1] = (m[2]*m[7]-m[1]*m[8])*id; o[2] = (m[1]*m[5]-m[2]*m[4])*id;
  o[3] = c10*id; o[4] = (m[0]*m[8]-m[2]*m[6])*id; o[5] = (m[2]*m[3]-m[0]*m[5])*id;
  o[6] = c20*id; o[7] = (m[1]*m[6]-m[0]*m[7])*id; o[8] = (m[0]*m[4]-m[1]*m[3])*id;
}
// double-cofactor inverse — used for Pp^-1 (cond ~1e6+, cancellation hedge)
DEV void inv3d(const float* mf_, float* o) {
  double m0=mf_[0], m1=mf_[1], m2=mf_[2], m3=mf_[3], m4=mf_[4],
         m5=mf_[5], m6=mf_[6], m7=mf_[7], m8=mf_[8];
  double c00 = m4*m8 - m5*m7;
  double c10 = m5*m6 - m3*m8;
  double c20 = m3*m7 - m4*m6;
  double det = m0*c00 + m1*c10 + m2*c20;
  double id = 1.0 / det;
  o[0] = (float)(c00*id); o[1] = (float)((m2*m7-m1*m8)*id); o[2] = (float)((m1*m5-m2*m4)*id);
  o[3] = (float)(c10*id); o[4] = (float)((m0*m8-m2*m6)*id); o[5] = (float)((m2*m3-m0*m5)*id);
  o[6] = (float)(c20*id); o[7] = (float)((m1*m6-m0*m7)*id); o[8] = (float)((m0*m4-m1*m3)*id);
}
DEV void symm(float* P) {
  float a = 0.5f*(P[1]+P[3]), b = 0.5f*(P[2]+P[6]), c = 0.5f*(P[5]+P[7]);
  P[1]=P[3]=a; P[2]=P[6]=b; P[5]=P[7]=c;
}
// packed state (m, Psym) <-> 9 floats
DEV void st_state(const float* m, const float* P, float* g) {
  g[0]=m[0]; g[1]=m[1]; g[2]=m[2];
  g[3]=P[0]; g[4]=P[1]; g[5]=P[2]; g[6]=P[4]; g[7]=P[5]; g[8]=P[8];
}
DEV void ld_state(const float* g, float* m, float* P) {
  m[0]=g[0]; m[1]=g[1]; m[2]=g[2];
  P[0]=g[3]; P[1]=g[4]; P[2]=g[5];
  P[3]=g[4]; P[4]=g[6]; P[5]=g[7];
  P[6]=g[5]; P[7]=g[7]; P[8]=g[8];
}

// ---------------- model ----------------
struct Model { float lam, v, kap, l4; };
DEV Model make_model(const float* varp, const float* ellp) {
  Model M; M.v = varp[0];
  float ell = ellp[0];
  M.lam = sqrtf(5.0f) / ell;
  M.kap = M.lam * M.lam / 3.0f;
  float l2 = M.lam * M.lam;
  M.l4 = l2 * l2;
  return M;
}
DEV void pinf(const Model& M, float* P) {
  float vk = M.v * M.kap;
  P[0]=M.v; P[1]=0;  P[2]=-vk;
  P[3]=0;   P[4]=vk; P[5]=0;
  P[6]=-vk; P[7]=0;  P[8]=M.v*M.l4;
}
DEV void make_AQ(const Model& M, float dt, float* A, float* Q) {
  float lam = M.lam, l2 = lam*lam, l3 = l2*lam, l4 = M.l4;
  float e = __expf(-lam * dt);
  float h = 0.5f * dt * dt;
  A[0] = e*(1.0f + dt*lam + h*l2);
  A[1] = e*(dt + 2.0f*h*lam);
  A[2] = e*h;
  A[3] = e*(-h*l3);
  A[4] = e*(1.0f + dt*lam - 2.0f*h*l2);
  A[5] = e*(dt - h*lam);
  A[6] = e*(-dt*l3 + h*l4);
  A[7] = e*(-3.0f*dt*l2 + 2.0f*h*l3);
  A[8] = e*(1.0f - 2.0f*dt*lam + h*l2);
  float vk = M.v * M.kap, vl4 = M.v * M.l4;
  float B[9];  // A * Pinf
#pragma unroll
  for (int i = 0; i < 3; ++i) {
    B[i*3+0] =  A[i*3+0]*M.v - A[i*3+2]*vk;
    B[i*3+1] =  A[i*3+1]*vk;
    B[i*3+2] = -A[i*3+0]*vk  + A[i*3+2]*vl4;
  }
  float Pi[9]; pinf(M, Pi);
#pragma unroll
  for (int i = 0; i < 3; ++i)
#pragma unroll
    for (int j = 0; j < 3; ++j)
      Q[i*3+j] = Pi[i*3+j] - (B[i*3]*A[j*3] + B[i*3+1]*A[j*3+1] + B[i*3+2]*A[j*3+2]);
}

// ---------------- filter scan element ----------------
struct FE { float A[9]; float b[3]; float C[9]; float h[3]; float J[9]; };

DEV FE fe_identity() {
  FE e;
#pragma unroll
  for (int i=0;i<9;++i){ e.A[i]=0.0f; e.C[i]=0.0f; e.J[i]=0.0f; }
  e.A[0]=e.A[4]=e.A[8]=1.0f;
  e.b[0]=e.b[1]=e.b[2]=0.0f; e.h[0]=e.h[1]=e.h[2]=0.0f;
  return e;
}
DEV void fe_store(const FE& e, float* g) {          // contiguous 33
#pragma unroll
  for (int i=0;i<9;++i) g[i]=e.A[i];
  g[9]=e.b[0]; g[10]=e.b[1]; g[11]=e.b[2];
#pragma unroll
  for (int i=0;i<9;++i) g[12+i]=e.C[i];
  g[21]=e.h[0]; g[22]=e.h[1]; g[23]=e.h[2];
#pragma unroll
  for (int i=0;i<9;++i) g[24+i]=e.J[i];
}
DEV FE fe_load(const float* g) {
  FE e;
#pragma unroll
  for (int i=0;i<9;++i) e.A[i]=g[i];
  e.b[0]=g[9]; e.b[1]=g[10]; e.b[2]=g[11];
#pragma unroll
  for (int i=0;i<9;++i) e.C[i]=g[12+i];
  e.h[0]=g[21]; e.h[1]=g[22]; e.h[2]=g[23];
#pragma unroll
  for (int i=0;i<9;++i) e.J[i]=g[24+i];
  return e;
}
// transposed (component-major) global layout: g[comp*n + idx] -> lane-coalesced
DEV void fe_storeT(const FE& e, float* g, int idx, int n) {
#pragma unroll
  for (int i=0;i<9;++i) g[i*n+idx]=e.A[i];
#pragma unroll
  for (int i=0;i<3;++i) g[(9+i)*n+idx]=e.b[i];
#pragma unroll
  for (int i=0;i<9;++i) g[(12+i)*n+idx]=e.C[i];
#pragma unroll
  for (int i=0;i<3;++i) g[(21+i)*n+idx]=e.h[i];
#pragma unroll
  for (int i=0;i<9;++i) g[(24+i)*n+idx]=e.J[i];
}
DEV FE fe_loadT(const float* g, int idx, int n) {
  FE e;
#pragma unroll
  for (int i=0;i<9;++i) e.A[i]=g[i*n+idx];
#pragma unroll
  for (int i=0;i<3;++i) e.b[i]=g[(9+i)*n+idx];
#pragma unroll
  for (int i=0;i<9;++i) e.C[i]=g[(12+i)*n+idx];
#pragma unroll
  for (int i=0;i<3;++i) e.h[i]=g[(21+i)*n+idx];
#pragma unroll
  for (int i=0;i<9;++i) e.J[i]=g[(24+i)*n+idx];
  return e;
}
// load (b,C) of a prefix element as a state (valid when prefix includes elem 0)
DEV void fe_loadT_state(const float* g, int idx, int n, float* m, float* P) {
#pragma unroll
  for (int i=0;i<3;++i) m[i]=g[(9+i)*n+idx];
#pragma unroll
  for (int i=0;i<9;++i) P[i]=g[(12+i)*n+idx];
}
DEV FE fe_shfl_up(const FE& e, int d) {
  FE o;
#pragma unroll
  for (int i=0;i<9;++i) o.A[i]=__shfl_up(e.A[i], d, 64);
#pragma unroll
  for (int i=0;i<3;++i) o.b[i]=__shfl_up(e.b[i], d, 64);
#pragma unroll
  for (int i=0;i<9;++i) o.C[i]=__shfl_up(e.C[i], d, 64);
#pragma unroll
  for (int i=0;i<3;++i) o.h[i]=__shfl_up(e.h[i], d, 64);
#pragma unroll
  for (int i=0;i<9;++i) o.J[i]=__shfl_up(e.J[i], d, 64);
  return o;
}
DEV FE build_felem(const Model& M, float dt, float obsf, float rf, float Rf_, bool first) {
  FE E;
  float r = rf, R = Rf_;
  float g = (obsf > 0.5f) ? 1.0f : 0.0f;
  if (first) {
#pragma unroll
    for (int i=0;i<9;++i){ E.A[i]=0.0f; E.J[i]=0.0f; }
    E.h[0]=E.h[1]=E.h[2]=0.0f;
    float Pi[9]; pinf(M, Pi);
    float S = Pi[0] + R;
    float f = g / S;
    float K0=Pi[0]*f, K1=Pi[3]*f, K2=Pi[6]*f;
    E.b[0]=K0*r; E.b[1]=K1*r; E.b[2]=K2*r;
    E.C[0]=Pi[0]-S*K0*K0; E.C[1]=Pi[1]-S*K0*K1; E.C[2]=Pi[2]-S*K0*K2;
    E.C[3]=Pi[3]-S*K1*K0; E.C[4]=Pi[4]-S*K1*K1; E.C[5]=Pi[5]-S*K1*K2;
    E.C[6]=Pi[6]-S*K2*K0; E.C[7]=Pi[7]-S*K2*K1; E.C[8]=Pi[8]-S*K2*K2;
    return E;
  }
  float Am[9], Q[9]; make_AQ(M, dt, Am, Q);
  float S = Q[0] + R, iS = g / S;   // gated: obs=0 -> K=0, A=Am, C=Q, h=0, J=0
  float K0=Q[0]*iS, K1=Q[3]*iS, K2=Q[6]*iS;
#pragma unroll
  for (int j = 0; j < 3; ++j) {
    E.A[j]   = Am[j]   - K0*Am[j];
    E.A[3+j] = Am[3+j] - K1*Am[j];
    E.A[6+j] = Am[6+j] - K2*Am[j];
    E.C[j]   = Q[j]    - K0*Q[j];
    E.C[3+j] = Q[3+j]  - K1*Q[j];
    E.C[6+j] = Q[6+j]  - K2*Q[j];
  }
  E.b[0]=K0*r; E.b[1]=K1*r; E.b[2]=K2*r;
  float riS = r*iS;
  E.h[0]=Am[0]*riS; E.h[1]=Am[1]*riS; E.h[2]=Am[2]*riS;
#pragma unroll
  for (int i = 0; i < 3; ++i)
#pragma unroll
    for (int j = 0; j < 3; ++j)
      E.J[i*3+j] = Am[i]*Am[j]*iS;
  return E;
}
// compose: x earlier, y later
DEV FE fcompose(const FE& x, const FE& y) {
  const float *A1=x.A,*b1=x.b,*C1=x.C,*h1=x.h,*J1=x.J;
  const float *A2=y.A,*b2=y.b,*C2=y.C,*h2=y.h,*J2=y.J;
  FE o;
  float Mx[9]; mm(C1,J2,Mx); Mx[0]+=1.0f; Mx[4]+=1.0f; Mx[8]+=1.0f;
  float Mi[9]; inv3f(Mx,Mi);
  float T1[9]; mm(A2,Mi,T1);
  mm(T1,A1,o.A);
  float u[3]; mv(C1,h2,u); u[0]+=b1[0]; u[1]+=b1[1]; u[2]+=b1[2];
  mv(T1,u,o.b); o.b[0]+=b2[0]; o.b[1]+=b2[1]; o.b[2]+=b2[2];
  float t2[9]; mm(T1,C1,t2);
  mmnt(t2,A2,o.C);
#pragma unroll
  for (int i=0;i<9;++i) o.C[i]+=C2[i];
  float tmp[9]; mm(Mi,A1,tmp);
  float w[3]; mv(J2,b1,w);
  w[0]=h2[0]-w[0]; w[1]=h2[1]-w[1]; w[2]=h2[2]-w[2];
  mtv(tmp,w,o.h); o.h[0]+=h1[0]; o.h[1]+=h1[1]; o.h[2]+=h1[2];
  float V[9]; mm(J2,A1,V);
  mtn(tmp,V,o.J);
#pragma unroll
  for (int i=0;i<9;++i) o.J[i]+=J1[i];
  symm(o.C); symm(o.J);
  return o;
}
// apply element y (later) to a state (m,P): reduced compose (A1=0,h1=0,J1=0)
DEV void fapply(const FE& y, float* m, float* P) {
  float Mx[9]; mm(P, y.J, Mx); Mx[0]+=1.0f; Mx[4]+=1.0f; Mx[8]+=1.0f;
  float Mi[9]; inv3f(Mx, Mi);
  float T1[9]; mm(y.A, Mi, T1);
  float u[3]; mv(P, y.h, u); u[0]+=m[0]; u[1]+=m[1]; u[2]+=m[2];
  float mn[3]; mv(T1, u, mn);
  m[0]=mn[0]+y.b[0]; m[1]=mn[1]+y.b[1]; m[2]=mn[2]+y.b[2];
  float t2[9]; mm(T1, P, t2);
  float Pn[9]; mmnt(t2, y.A, Pn);
#pragma unroll
  for (int i=0;i<9;++i) P[i]=Pn[i]+y.C[i];
  symm(P);
}
// plain Kalman step (replay)
DEV void fstep(const Model& M, float dt, float obsf, float rf, float Rf_,
               float* m, float* P) {
  float A[9], Q[9]; make_AQ(M, dt, A, Q);
  float mp[3]; mv(A, m, mp);
  float W[9]; mmnt(P, A, W);      // P A^T
  float Pp[9]; mm(A, W, Pp);
#pragma unroll
  for (int i=0;i<9;++i) Pp[i]+=Q[i];
  float S = Pp[0] + Rf_;
  float f = (obsf > 0.5f) ? (1.0f/S) : 0.0f;
  float K0=Pp[0]*f, K1=Pp[3]*f, K2=Pp[6]*f;
  float v = rf - mp[0];
  m[0]=mp[0]+K0*v; m[1]=mp[1]+K1*v; m[2]=mp[2]+K2*v;
  P[0]=Pp[0]-S*K0*K0; P[1]=Pp[1]-S*K0*K1; P[2]=Pp[2]-S*K0*K2;
  P[3]=Pp[3]-S*K1*K0; P[4]=Pp[4]-S*K1*K1; P[5]=Pp[5]-S*K1*K2;
  P[6]=Pp[6]-S*K2*K0; P[7]=Pp[7]-S*K2*K1; P[8]=Pp[8]-S*K2*K2;
  symm(P);
}

// ---------------- smoother affine map: x_k = G x_{k+1} + c ; P_k = G P G^T + U ----------------
struct SE { float G[9]; float c[3]; float U[9]; };

DEV SE se_identity() {
  SE s;
#pragma unroll
  for (int i=0;i<9;++i){ s.G[i]=0.0f; s.U[i]=0.0f; }
  s.G[0]=s.G[4]=s.G[8]=1.0f;
  s.c[0]=s.c[1]=s.c[2]=0.0f;
  return s;
}
DEV void se_store(const SE& s, float* g) {   // contiguous packed-18
#pragma unroll
  for (int i=0;i<9;++i) g[i]=s.G[i];
  g[9]=s.c[0]; g[10]=s.c[1]; g[11]=s.c[2];
  g[12]=s.U[0]; g[13]=s.U[1]; g[14]=s.U[2]; g[15]=s.U[4]; g[16]=s.U[5]; g[17]=s.U[8];
}
DEV SE se_load(const float* g) {
  SE s;
#pragma unroll
  for (int i=0;i<9;++i) s.G[i]=g[i];
  s.c[0]=g[9]; s.c[1]=g[10]; s.c[2]=g[11];
  s.U[0]=g[12]; s.U[1]=g[13]; s.U[2]=g[14];
  s.U[3]=g[13]; s.U[4]=g[15]; s.U[5]=g[16];
  s.U[6]=g[14]; s.U[7]=g[16]; s.U[8]=g[17];
  return s;
}
DEV void se_storeT(const SE& s, float* g, int idx, int n) {  // component-major
#pragma unroll
  for (int i=0;i<9;++i) g[i*n+idx]=s.G[i];
#pragma unroll
  for (int i=0;i<3;++i) g[(9+i)*n+idx]=s.c[i];
  g[12*n+idx]=s.U[0]; g[13*n+idx]=s.U[1]; g[14*n+idx]=s.U[2];
  g[15*n+idx]=s.U[4]; g[16*n+idx]=s.U[5]; g[17*n+idx]=s.U[8];
}
DEV SE se_loadT(const float* g, int idx, int n) {
  SE s;
#pragma unroll
  for (int i=0;i<9;++i) s.G[i]=g[i*n+idx];
#pragma unroll
  for (int i=0;i<3;++i) s.c[i]=g[(9+i)*n+idx];
  float u0=g[12*n+idx], u1=g[13*n+idx], u2=g[14*n+idx],
        u4=g[15*n+idx], u5=g[16*n+idx], u8=g[17*n+idx];
  s.U[0]=u0; s.U[1]=u1; s.U[2]=u2;
  s.U[3]=u1; s.U[4]=u4; s.U[5]=u5;
  s.U[6]=u2; s.U[7]=u5; s.U[8]=u8;
  return s;
}
DEV SE se_shfl_down(const SE& s, int d) {
  SE o;
#pragma unroll
  for (int i=0;i<9;++i) o.G[i]=__shfl_down(s.G[i], d, 64);
#pragma unroll
  for (int i=0;i<3;++i) o.c[i]=__shfl_down(s.c[i], d, 64);
#pragma unroll
  for (int i=0;i<9;++i) o.U[i]=__shfl_down(s.U[i], d, 64);
  return o;
}
// x earlier in time (applied LAST, since smoother runs backward)
DEV SE scompose(const SE& x, const SE& y) {
  SE o;
  mm(x.G, y.G, o.G);
  float t[3]; mv(x.G, y.c, t);
  o.c[0]=t[0]+x.c[0]; o.c[1]=t[1]+x.c[1]; o.c[2]=t[2]+x.c[2];
  float T[9]; mm(x.G, y.U, T);
  mmnt(T, x.G, o.U);
#pragma unroll
  for (int i=0;i<9;++i) o.U[i]+=x.U[i];
  symm(o.U);
  return o;
}
DEV void sapply(const SE& s, float* m, float* P) {
  float t[3]; mv(s.G, m, t);
  float T[9]; mm(s.G, P, T);
  float Pn[9]; mmnt(T, s.G, Pn);
  m[0]=t[0]+s.c[0]; m[1]=t[1]+s.c[1]; m[2]=t[2]+s.c[2];
#pragma unroll
  for (int i=0;i<9;++i) P[i]=Pn[i]+s.U[i];
  symm(P);
}
// smoother element from filtered register state (m,P) at k, dt to k+1
DEV SE selem_from_state(const Model& M, const float* m, const float* P, float dtn) {
  SE s;
  float A[9], Q[9]; make_AQ(M, dtn, A, Q);
  float W[9]; mmnt(P, A, W);      // P A^T
  float Pp[9]; mm(A, W, Pp);
#pragma unroll
  for (int j=0;j<9;++j) Pp[j]+=Q[j];
  float Pi_[9]; inv3d(Pp, Pi_);    // ill-conditioned -> double cofactors
  mm(W, Pi_, s.G);                 // G = P A^T Pp^-1
  float mp[3]; mv(A, m, mp);
  float gm[3]; mv(s.G, mp, gm);
  s.c[0]=m[0]-gm[0]; s.c[1]=m[1]-gm[1]; s.c[2]=m[2]-gm[2];
  float GW[9]; mmnt(s.G, W, GW);   // G Pp G^T
#pragma unroll
  for (int j=0;j<9;++j) s.U[j]=P[j]-GW[j];
  symm(s.U);
  return s;
}

// ================= kernels =================
// pk[k] = {time, residual, R, is_obs}  (natural order)
__global__ void k_merge(const float* __restrict__ times, const float* __restrict__ tstar,
                        const float* __restrict__ n1, const float* __restrict__ n2,
                        const float* __restrict__ mcp,
                        float4* pk, int* oix) {
  int g = blockIdx.x*blockDim.x + threadIdx.x;
  if (g >= T_TOT) return;
  float mc = mcp[0];
  if (g < N_TRAIN) {
    int i = g;
    float t = times[i];
    int lo = 0, hi = M_TEST;                 // count tstar strictly < t
    while (lo < hi) { int mid=(lo+hi)>>1; if (tstar[mid] < t) lo=mid+1; else hi=mid; }
    int p = i + lo;
    float s2 = n2[i];
    pk[p] = make_float4(t, n1[i]/s2 - mc, 1.0f/s2, 1.0f);
    oix[p] = -1;
  } else {
    int j = g - N_TRAIN;
    float t = tstar[j];
    int lo = 0, hi = N_TRAIN;                // count times <= t (stable: train first)
    while (lo < hi) { int mid=(lo+hi)>>1; if (times[mid] <= t) lo=mid+1; else hi=mid; }
    int p = j + lo;
    pk[p] = make_float4(t, 0.f, 1.f, 0.f);
    oix[p] = j;
  }
}

// F1: one element per thread, 64-wide shuffle inclusive scan.
__global__ __launch_bounds__(TPB, 3) void k_f1(
    const float* varp, const float* ellp, const float4* __restrict__ pk,
    float* tIncl, float* blkAgg) {
  int l = threadIdx.x, b = blockIdx.x;
  int t = b*TPB + l;
  Model M = make_model(varp, ellp);
  float4 q = pk[t];
  float dt = (t == 0) ? 0.0f : (q.x - pk[t-1].x);
  FE run = build_felem(M, dt, q.w, q.y, q.z, t == 0);
  for (int d = 1; d < TPB; d <<= 1) {
    FE oth = fe_shfl_up(run, d);
    FE comp = fcompose(oth, run);
    if (l >= d) run = comp;
  }
  fe_storeT(run, tIncl, t, T_TOT);
  if (l == TPB-1) fe_storeT(run, blkAgg, b, NBLK);
}

// F2a: 48 blocks x 64; shuffle-scan 64 block aggregates each -> blkIncl2, group agg.
__global__ __launch_bounds__(TPB, 2) void k_f2a(const float* __restrict__ blkAgg,
                                                float* blkIncl2, float* grpAgg) {
  int l = threadIdx.x, gb = blockIdx.x;
  int b = gb*GRP + l;
  FE run = fe_loadT(blkAgg, b, NBLK);
  for (int d = 1; d < TPB; d <<= 1) {
    FE oth = fe_shfl_up(run, d);
    FE comp = fcompose(oth, run);
    if (l >= d) run = comp;
  }
  fe_storeT(run, blkIncl2, b, NBLK);
  if (l == GRP-1) fe_store(run, grpAgg + gb*FE_S);
}

// F2b: one 64-thread block shuffle-scans the 48 group aggregates -> exclusive prefix.
__global__ __launch_bounds__(TPB, 2) void k_f2b(const float* __restrict__ grpAgg,
                                                float* grpPref) {
  int j = threadIdx.x;
  FE run = (j < NGRP) ? fe_load(grpAgg + j*FE_S) : fe_identity();
  for (int d = 1; d < TPB; d <<= 1) {
    FE oth = fe_shfl_up(run, d);
    FE comp = fcompose(oth, run);
    if (j >= d) run = comp;
  }
  FE X = fe_shfl_up(run, 1);
  if (j < NGRP) {
    if (j == 0) X = fe_identity();
    fe_store(X, grpPref + j*FE_S);
  }
}

// F3 (+fused s1): entry state (<=2 fapplys) + fstep + smoother element in regs +
// backward in-wave suffix scan; store row-0 (5 floats) + lane0 block aggregate.
__global__ __launch_bounds__(TPB, 3) void k_f3(
    const float* varp, const float* ellp, const float4* __restrict__ pk,
    const float* __restrict__ tIncl, const float* __restrict__ blkIncl2,
    const float* __restrict__ grpPref,
    float* out5, float* blkAggS, float* xT) {
  int l = threadIdx.x, b = blockIdx.x;
  int t = b*TPB + l;
  int g = b >> 6, lb = b & (GRP-1);
  Model M = make_model(varp, ellp);
  float m[3], P[9];
  if (t == 0) {
    m[0]=m[1]=m[2]=0.0f; pinf(M, P);
  } else if (g == 0 && lb == 0) {            // block 0: tIncl[t-1] is a state
    fe_loadT_state(tIncl, t-1, T_TOT, m, P);
  } else if (g == 0) {                        // group 0: blkIncl2[b-1] is a state
    fe_loadT_state(blkIncl2, b-1, NBLK, m, P);
    if (l > 0) { FE y = fe_loadT(tIncl, t-1, T_TOT); fapply(y, m, P); }
  } else {                                    // grpPref[g] is a state
    const float* gp = grpPref + g*FE_S;
    m[0]=gp[9]; m[1]=gp[10]; m[2]=gp[11];
#pragma unroll
    for (int i=0;i<9;++i) P[i]=gp[12+i];
    if (lb > 0) { FE y = fe_loadT(blkIncl2, b-1, NBLK); fapply(y, m, P); }
    if (l  > 0) { FE y = fe_loadT(tIncl,  t-1, T_TOT); fapply(y, m, P); }
  }
  float4 q = pk[t];
  float dt = (t == 0) ? 0.0f : (q.x - pk[t-1].x);
  fstep(M, dt, q.w, q.y, q.z, m, P);
  SE e;
  if (t < T_TOT-1) {
    float dtn = pk[t+1].x - q.x;
    e = selem_from_state(M, m, P, dtn);
  } else {
    e = se_identity();
    xT[0]=m[0]; xT[1]=m[1]; xT[2]=m[2];
    xT[3]=P[0]; xT[4]=P[1]; xT[5]=P[2];
    xT[6]=P[4]; xT[7]=P[5]; xT[8]=P[8];
  }
  // backward in-wave suffix scan: Macc[l] = e_l ∘ ... ∘ e_63
  SE Macc = e;
  for (int d = 1; d < TPB; d <<= 1) {
    SE oth = se_shfl_down(Macc, d);
    SE c = scompose(Macc, oth);
    if (l + d < TPB) Macc = c;
  }
  // row-0 of the map is all s3 needs for (m0, P00)
  out5[0*T_TOT+t] = Macc.G[0];
  out5[1*T_TOT+t] = Macc.G[1];
  out5[2*T_TOT+t] = Macc.G[2];
  out5[3*T_TOT+t] = Macc.c[0];
  out5[4*T_TOT+t] = Macc.U[0];
  if (l == 0) se_storeT(Macc, blkAggS, b, NBLK);
}

// S2a: 48 blocks x 64; shuffle backward scan of block aggregates -> blkSuf2, group agg.
__global__ __launch_bounds__(TPB, 2) void k_s2a(const float* __restrict__ blkAggS,
                                                float* blkSuf2, float* grpAggS) {
  int l = threadIdx.x, gb = blockIdx.x;
  int b = gb*GRP + l;
  SE run = se_loadT(blkAggS, b, NBLK);
  for (int d = 1; d < TPB; d <<= 1) {
    SE oth = se_shfl_down(run, d);
    SE comp = scompose(run, oth);
    if (l + d < TPB) run = comp;
  }
  se_storeT(run, blkSuf2, b, NBLK);
  if (l == 0) se_store(run, grpAggS + gb*18);
}

// S2b: one 64-thread block backward-scans 48 group aggregates -> gExit[g] =
// smoothed state at first index of group g+1 (last group: xT).
__global__ __launch_bounds__(TPB, 2) void k_s2b(const float* __restrict__ grpAggS,
                                                const float* __restrict__ xT,
                                                float* gExit) {
  int j = threadIdx.x;
  SE run = (j < NGRP) ? se_load(grpAggS + j*18) : se_identity();
  for (int d = 1; d < TPB; d <<= 1) {
    SE oth = se_shfl_down(run, d);
    SE comp = scompose(run, oth);
    if (j + d < TPB) run = comp;
  }
  SE Sx = se_shfl_down(run, 1);   // suffix of groups j+1..
  if (j < NGRP) {
    float m[3] = { xT[0], xT[1], xT[2] };
    float P[9] = { xT[3],xT[4],xT[5], xT[4],xT[6],xT[7], xT[5],xT[7],xT[8] };
    if (j < NGRP-1) sapply(Sx, m, P);
    st_state(m, P, gExit + j*9);
  }
}

// S3: gExit[g] -> (blkSuf2[b+1]) -> row0(Macc[t]); write output.
__global__ __launch_bounds__(256, 4) void k_s3(
    const float* mcp, const float* __restrict__ out5,
    const float* __restrict__ blkSuf2, const float* __restrict__ gExit,
    const int* __restrict__ oix, float* out) {
  int t = blockIdx.x*256 + threadIdx.x;
  int b = t >> 6;
  int g = b >> 6, lb = b & (GRP-1);
  float mc = mcp[0];
  float m[3], P[9];
  ld_state(gExit + g*9, m, P);
  if (lb < GRP-1) {                  // -> state at first index of block b+1
    SE s = se_loadT(blkSuf2, b+1, NBLK);
    sapply(s, m, P);
  }
  float g0 = out5[0*T_TOT+t], g1 = out5[1*T_TOT+t], g2 = out5[2*T_TOT+t];
  float c0 = out5[3*T_TOT+t], u00 = out5[4*T_TOT+t];
  float mm0 = g0*m[0] + g1*m[1] + g2*m[2] + c0;
  float q0 = g0*P[0] + g1*P[3] + g2*P[6];
  float q1 = g0*P[1] + g1*P[4] + g2*P[7];
  float q2 = g0*P[2] + g1*P[5] + g2*P[8];
  float v00 = q0*g0 + q1*g1 + q2*g2 + u00;
  int j = oix[t];
  if (j >= 0) { out[j] = mm0 + mc; out[M_TEST + j] = fmaxf(v00, 0.0f); }
}

extern "C" void kernel_launch(void* const* d_in, const int* in_sizes, int n_in,
                              void* d_out, int out_size, void* d_ws, size_t ws_size,
                              hipStream_t stream) {
  const float* times = (const float*)d_in[0];
  const float* tstar = (const float*)d_in[1];
  const float* n1    = (const float*)d_in[2];
  const float* n2    = (const float*)d_in[3];
  const float* varp  = (const float*)d_in[4];
  const float* ellp  = (const float*)d_in[5];
  const float* mcp   = (const float*)d_in[6];
  float* out = (float*)d_out;

  size_t off = 0;
  auto take = [&](size_t bytes) {
    char* p = (char*)d_ws + off;
    off += (bytes + 255) & ~(size_t)255;
    return (void*)p;
  };
  float4* pk     = (float4*)take(sizeof(float4) * T_TOT);
  int*    oix    = (int*)   take(sizeof(int)    * T_TOT);
  float*  tIncl  = (float*) take(sizeof(float)  * FE_S * T_TOT);
  float*  blkAgg = (float*) take(sizeof(float)  * FE_S * NBLK);
  float*  blkIncl2=(float*) take(sizeof(float)  * FE_S * NBLK);
  float*  grpAgg = (float*) take(sizeof(float)  * FE_S * NGRP);
  float*  grpPref= (float*) take(sizeof(float)  * FE_S * NGRP);
  float*  out5   = (float*) take(sizeof(float)  * 5  * T_TOT);
  float*  blkAggS= (float*) take(sizeof(float)  * 18 * NBLK);
  float*  blkSuf2= (float*) take(sizeof(float)  * 18 * NBLK);
  float*  grpAggS= (float*) take(sizeof(float)  * 18 * NGRP);
  float*  gExit  = (float*) take(sizeof(float)  * 9  * NGRP);
  float*  xT     = (float*) take(sizeof(float)  * 9);
  (void)ws_size; (void)in_sizes; (void)n_in; (void)out_size;

  k_merge<<<(T_TOT+255)/256, 256, 0, stream>>>(times, tstar, n1, n2, mcp, pk, oix);
  k_f1   <<<NBLK, TPB, 0, stream>>>(varp, ellp, pk, tIncl, blkAgg);
  k_f2a  <<<NGRP, TPB, 0, stream>>>(blkAgg, blkIncl2, grpAgg);
  k_f2b  <<<1, TPB, 0, stream>>>(grpAgg, grpPref);
  k_f3   <<<NBLK, TPB, 0, stream>>>(varp, ellp, pk, tIncl, blkIncl2, grpPref, out5, blkAggS, xT);
  k_s2a  <<<NGRP, TPB, 0, stream>>>(blkAggS, blkSuf2, grpAggS);
  k_s2b  <<<1, TPB, 0, stream>>>(grpAggS, xT, gExit);
  k_s3   <<<T_TOT/256, 256, 0, stream>>>(mcp, out5, blkSuf2, gExit, oix, out);
}

// Round 14
// 143.070 us; speedup vs baseline: 1.5098x; 1.0058x over previous
//
#include <hip/hip_runtime.h>
#include <math.h>

#define DEV __device__ __forceinline__

constexpr int N_TRAIN = 131072;
constexpr int M_TEST  = 65536;
constexpr int T_TOT   = N_TRAIN + M_TEST;  // 196608
constexpr int TPB     = 64;                // single-wave blocks
constexpr int NBLK    = T_TOT / TPB;       // 3072 level-1 blocks
constexpr int GRP     = 64;                // blocks per group
constexpr int NGRP    = NBLK / GRP;        // 48 groups
constexpr int FE_P    = 27;                // packed FE record (floats)

// ---------------- 3x3 helpers (row-major float[9]) ----------------
DEV void mm(const float* X, const float* Y, float* Z) {
#pragma unroll
  for (int i = 0; i < 3; ++i)
#pragma unroll
    for (int j = 0; j < 3; ++j)
      Z[i*3+j] = X[i*3]*Y[j] + X[i*3+1]*Y[3+j] + X[i*3+2]*Y[6+j];
}
DEV void mmnt(const float* X, const float* Y, float* Z) { // X * Y^T
#pragma unroll
  for (int i = 0; i < 3; ++i)
#pragma unroll
    for (int j = 0; j < 3; ++j)
      Z[i*3+j] = X[i*3]*Y[j*3] + X[i*3+1]*Y[j*3+1] + X[i*3+2]*Y[j*3+2];
}
DEV void mtn(const float* X, const float* Y, float* Z) { // X^T * Y
#pragma unroll
  for (int i = 0; i < 3; ++i)
#pragma unroll
    for (int j = 0; j < 3; ++j)
      Z[i*3+j] = X[i]*Y[j] + X[3+i]*Y[3+j] + X[6+i]*Y[6+j];
}
DEV void mv(const float* X, const float* v, float* w) {
#pragma unroll
  for (int i = 0; i < 3; ++i) w[i] = X[i*3]*v[0] + X[i*3+1]*v[1] + X[i*3+2]*v[2];
}
DEV void mtv(const float* X, const float* v, float* w) {
#pragma unroll
  for (int i = 0; i < 3; ++i) w[i] = X[i]*v[0] + X[3+i]*v[1] + X[6+i]*v[2];
}
// fp32 inverse — used for Mx = I + C*J (det>=1, well-conditioned)
DEV void inv3f(const float* m, float* o) {
  float c00 = m[4]*m[8] - m[5]*m[7];
  float c10 = m[5]*m[6] - m[3]*m[8];
  float c20 = m[3]*m[7] - m[4]*m[6];
  float det = m[0]*c00 + m[1]*c10 + m[2]*c20;
  float id = 1.0f / det;
  o[0] = c00*id; o[1] = (m[2]*m[7]-m[1]*m[8])*id; o[2] = (m[1]*m[5]-m[2]*m[4])*id;
  o[3] = c10*id; o[4] = (m[0]*m[8]-m[2]*m[6])*id; o[5] = (m[2]*m[3]-m[0]*m[5])*id;
  o[6] = c20*id; o[7] = (m[1]*m[6]-m[0]*m[7])*id; o[8] = (m[0]*m[4]-m[1]*m[3])*id;
}
// double-cofactor inverse — used for Pp^-1 (cond ~1e6+, cancellation hedge)
DEV void inv3d(const float* mf_, float* o) {
  double m0=mf_[0], m1=mf_[1], m2=mf_[2], m3=mf_[3], m4=mf_[4],
         m5=mf_[5], m6=mf_[6], m7=mf_[7], m8=mf_[8];
  double c00 = m4*m8 - m5*m7;
  double c10 = m5*m6 - m3*m8;
  double c20 = m3*m7 - m4*m6;
  double det = m0*c00 + m1*c10 + m2*c20;
  double id = 1.0 / det;
  o[0] = (float)(c00*id); o[1] = (float)((m2*m7-m1*m8)*id); o[2] = (float)((m1*m5-m2*m4)*id);
  o[3] = (float)(c10*id); o[4] = (float)((m0*m8-m2*m6)*id); o[5] = (float)((m2*m3-m0*m5)*id);
  o[6] = (float)(c20*id); o[7] = (float)((m1*m6-m0*m7)*id); o[8] = (float)((m0*m4-m1*m3)*id);
}
DEV void symm(float* P) {
  float a = 0.5f*(P[1]+P[3]), b = 0.5f*(P[2]+P[6]), c = 0.5f*(P[5]+P[7]);
  P[1]=P[3]=a; P[2]=P[6]=b; P[5]=P[7]=c;
}
// packed state (m, Psym) <-> 9 floats
DEV void st_state(const float* m, const float* P, float* g) {
  g[0]=m[0]; g[1]=m[1]; g[2]=m[2];
  g[3]=P[0]; g[4]=P[1]; g[5]=P[2]; g[6]=P[4]; g[7]=P[5]; g[8]=P[8];
}
DEV void ld_state(const float* g, float* m, float* P) {
  m[0]=g[0]; m[1]=g[1]; m[2]=g[2];
  P[0]=g[3]; P[1]=g[4]; P[2]=g[5];
  P[3]=g[4]; P[4]=g[6]; P[5]=g[7];
  P[6]=g[5]; P[7]=g[7]; P[8]=g[8];
}

// ---------------- model ----------------
struct Model { float lam, v, kap, l4; };
DEV Model make_model(const float* varp, const float* ellp) {
  Model M; M.v = varp[0];
  float ell = ellp[0];
  M.lam = sqrtf(5.0f) / ell;
  M.kap = M.lam * M.lam / 3.0f;
  float l2 = M.lam * M.lam;
  M.l4 = l2 * l2;
  return M;
}
DEV void pinf(const Model& M, float* P) {
  float vk = M.v * M.kap;
  P[0]=M.v; P[1]=0;  P[2]=-vk;
  P[3]=0;   P[4]=vk; P[5]=0;
  P[6]=-vk; P[7]=0;  P[8]=M.v*M.l4;
}
DEV void make_AQ(const Model& M, float dt, float* A, float* Q) {
  float lam = M.lam, l2 = lam*lam, l3 = l2*lam, l4 = M.l4;
  float e = __expf(-lam * dt);
  float h = 0.5f * dt * dt;
  A[0] = e*(1.0f + dt*lam + h*l2);
  A[1] = e*(dt + 2.0f*h*lam);
  A[2] = e*h;
  A[3] = e*(-h*l3);
  A[4] = e*(1.0f + dt*lam - 2.0f*h*l2);
  A[5] = e*(dt - h*lam);
  A[6] = e*(-dt*l3 + h*l4);
  A[7] = e*(-3.0f*dt*l2 + 2.0f*h*l3);
  A[8] = e*(1.0f - 2.0f*dt*lam + h*l2);
  float vk = M.v * M.kap, vl4 = M.v * M.l4;
  float B[9];  // A * Pinf
#pragma unroll
  for (int i = 0; i < 3; ++i) {
    B[i*3+0] =  A[i*3+0]*M.v - A[i*3+2]*vk;
    B[i*3+1] =  A[i*3+1]*vk;
    B[i*3+2] = -A[i*3+0]*vk  + A[i*3+2]*vl4;
  }
  float Pi[9]; pinf(M, Pi);
#pragma unroll
  for (int i = 0; i < 3; ++i)
#pragma unroll
    for (int j = 0; j < 3; ++j)
      Q[i*3+j] = Pi[i*3+j] - (B[i*3]*A[j*3] + B[i*3+1]*A[j*3+1] + B[i*3+2]*A[j*3+2]);
}

// ---------------- filter scan element ----------------
struct FE { float A[9]; float b[3]; float C[9]; float h[3]; float J[9]; };

DEV FE fe_identity() {
  FE e;
#pragma unroll
  for (int i=0;i<9;++i){ e.A[i]=0.0f; e.C[i]=0.0f; e.J[i]=0.0f; }
  e.A[0]=e.A[4]=e.A[8]=1.0f;
  e.b[0]=e.b[1]=e.b[2]=0.0f; e.h[0]=e.h[1]=e.h[2]=0.0f;
  return e;
}
// packed-27 contiguous: [A0..8][b0..2][C00,C01,C02,C11,C12,C22][h0..2][J00,J01,J02,J11,J12,J22]
DEV void fe_store27(const FE& e, float* g) {
#pragma unroll
  for (int i=0;i<9;++i) g[i]=e.A[i];
  g[9]=e.b[0]; g[10]=e.b[1]; g[11]=e.b[2];
  g[12]=e.C[0]; g[13]=e.C[1]; g[14]=e.C[2]; g[15]=e.C[4]; g[16]=e.C[5]; g[17]=e.C[8];
  g[18]=e.h[0]; g[19]=e.h[1]; g[20]=e.h[2];
  g[21]=e.J[0]; g[22]=e.J[1]; g[23]=e.J[2]; g[24]=e.J[4]; g[25]=e.J[5]; g[26]=e.J[8];
}
DEV FE fe_load27(const float* g) {
  FE e;
#pragma unroll
  for (int i=0;i<9;++i) e.A[i]=g[i];
  e.b[0]=g[9]; e.b[1]=g[10]; e.b[2]=g[11];
  e.C[0]=g[12]; e.C[1]=g[13]; e.C[2]=g[14]; e.C[3]=g[13]; e.C[4]=g[15];
  e.C[5]=g[16]; e.C[6]=g[14]; e.C[7]=g[16]; e.C[8]=g[17];
  e.h[0]=g[18]; e.h[1]=g[19]; e.h[2]=g[20];
  e.J[0]=g[21]; e.J[1]=g[22]; e.J[2]=g[23]; e.J[3]=g[22]; e.J[4]=g[24];
  e.J[5]=g[25]; e.J[6]=g[23]; e.J[7]=g[25]; e.J[8]=g[26];
  return e;
}
// packed-27, component-major (stride n) -> lane-coalesced
DEV void fe_storeT(const FE& e, float* g, int idx, int n) {
#pragma unroll
  for (int i=0;i<9;++i) g[i*n+idx]=e.A[i];
#pragma unroll
  for (int i=0;i<3;++i) g[(9+i)*n+idx]=e.b[i];
  g[12*n+idx]=e.C[0]; g[13*n+idx]=e.C[1]; g[14*n+idx]=e.C[2];
  g[15*n+idx]=e.C[4]; g[16*n+idx]=e.C[5]; g[17*n+idx]=e.C[8];
#pragma unroll
  for (int i=0;i<3;++i) g[(18+i)*n+idx]=e.h[i];
  g[21*n+idx]=e.J[0]; g[22*n+idx]=e.J[1]; g[23*n+idx]=e.J[2];
  g[24*n+idx]=e.J[4]; g[25*n+idx]=e.J[5]; g[26*n+idx]=e.J[8];
}
DEV FE fe_loadT(const float* g, int idx, int n) {
  FE e;
#pragma unroll
  for (int i=0;i<9;++i) e.A[i]=g[i*n+idx];
#pragma unroll
  for (int i=0;i<3;++i) e.b[i]=g[(9+i)*n+idx];
  float c0=g[12*n+idx], c1=g[13*n+idx], c2=g[14*n+idx],
        c4=g[15*n+idx], c5=g[16*n+idx], c8=g[17*n+idx];
  e.C[0]=c0; e.C[1]=c1; e.C[2]=c2; e.C[3]=c1; e.C[4]=c4; e.C[5]=c5;
  e.C[6]=c2; e.C[7]=c5; e.C[8]=c8;
#pragma unroll
  for (int i=0;i<3;++i) e.h[i]=g[(18+i)*n+idx];
  float j0=g[21*n+idx], j1=g[22*n+idx], j2=g[23*n+idx],
        j4=g[24*n+idx], j5=g[25*n+idx], j8=g[26*n+idx];
  e.J[0]=j0; e.J[1]=j1; e.J[2]=j2; e.J[3]=j1; e.J[4]=j4; e.J[5]=j5;
  e.J[6]=j2; e.J[7]=j5; e.J[8]=j8;
  return e;
}
// load (b,C) of a prefix element as a state (valid when prefix includes elem 0)
DEV void fe_loadT_state(const float* g, int idx, int n, float* m, float* P) {
#pragma unroll
  for (int i=0;i<3;++i) m[i]=g[(9+i)*n+idx];
  float c0=g[12*n+idx], c1=g[13*n+idx], c2=g[14*n+idx],
        c4=g[15*n+idx], c5=g[16*n+idx], c8=g[17*n+idx];
  P[0]=c0; P[1]=c1; P[2]=c2; P[3]=c1; P[4]=c4; P[5]=c5; P[6]=c2; P[7]=c5; P[8]=c8;
}
// wave shuffle of FE, packed 27 (C/J symmetric)
DEV FE fe_shfl_up(const FE& e, int d) {
  FE o;
#pragma unroll
  for (int i=0;i<9;++i) o.A[i]=__shfl_up(e.A[i], d, 64);
#pragma unroll
  for (int i=0;i<3;++i) o.b[i]=__shfl_up(e.b[i], d, 64);
  float c0=__shfl_up(e.C[0],d,64), c1=__shfl_up(e.C[1],d,64), c2=__shfl_up(e.C[2],d,64),
        c4=__shfl_up(e.C[4],d,64), c5=__shfl_up(e.C[5],d,64), c8=__shfl_up(e.C[8],d,64);
  o.C[0]=c0; o.C[1]=c1; o.C[2]=c2; o.C[3]=c1; o.C[4]=c4; o.C[5]=c5;
  o.C[6]=c2; o.C[7]=c5; o.C[8]=c8;
#pragma unroll
  for (int i=0;i<3;++i) o.h[i]=__shfl_up(e.h[i], d, 64);
  float j0=__shfl_up(e.J[0],d,64), j1=__shfl_up(e.J[1],d,64), j2=__shfl_up(e.J[2],d,64),
        j4=__shfl_up(e.J[4],d,64), j5=__shfl_up(e.J[5],d,64), j8=__shfl_up(e.J[8],d,64);
  o.J[0]=j0; o.J[1]=j1; o.J[2]=j2; o.J[3]=j1; o.J[4]=j4; o.J[5]=j5;
  o.J[6]=j2; o.J[7]=j5; o.J[8]=j8;
  return o;
}
DEV FE build_felem(const Model& M, float dt, float obsf, float rf, float Rf_, bool first) {
  FE E;
  float r = rf, R = Rf_;
  float g = (obsf > 0.5f) ? 1.0f : 0.0f;
  if (first) {
#pragma unroll
    for (int i=0;i<9;++i){ E.A[i]=0.0f; E.J[i]=0.0f; }
    E.h[0]=E.h[1]=E.h[2]=0.0f;
    float Pi[9]; pinf(M, Pi);
    float S = Pi[0] + R;
    float f = g / S;
    float K0=Pi[0]*f, K1=Pi[3]*f, K2=Pi[6]*f;
    E.b[0]=K0*r; E.b[1]=K1*r; E.b[2]=K2*r;
    E.C[0]=Pi[0]-S*K0*K0; E.C[1]=Pi[1]-S*K0*K1; E.C[2]=Pi[2]-S*K0*K2;
    E.C[3]=Pi[3]-S*K1*K0; E.C[4]=Pi[4]-S*K1*K1; E.C[5]=Pi[5]-S*K1*K2;
    E.C[6]=Pi[6]-S*K2*K0; E.C[7]=Pi[7]-S*K2*K1; E.C[8]=Pi[8]-S*K2*K2;
    return E;
  }
  float Am[9], Q[9]; make_AQ(M, dt, Am, Q);
  float S = Q[0] + R, iS = g / S;   // gated: obs=0 -> K=0, A=Am, C=Q, h=0, J=0
  float K0=Q[0]*iS, K1=Q[3]*iS, K2=Q[6]*iS;
#pragma unroll
  for (int j = 0; j < 3; ++j) {
    E.A[j]   = Am[j]   - K0*Am[j];
    E.A[3+j] = Am[3+j] - K1*Am[j];
    E.A[6+j] = Am[6+j] - K2*Am[j];
    E.C[j]   = Q[j]    - K0*Q[j];
    E.C[3+j] = Q[3+j]  - K1*Q[j];
    E.C[6+j] = Q[6+j]  - K2*Q[j];
  }
  E.b[0]=K0*r; E.b[1]=K1*r; E.b[2]=K2*r;
  float riS = r*iS;
  E.h[0]=Am[0]*riS; E.h[1]=Am[1]*riS; E.h[2]=Am[2]*riS;
#pragma unroll
  for (int i = 0; i < 3; ++i)
#pragma unroll
    for (int j = 0; j < 3; ++j)
      E.J[i*3+j] = Am[i]*Am[j]*iS;
  return E;
}
// compose: x earlier, y later
DEV FE fcompose(const FE& x, const FE& y) {
  const float *A1=x.A,*b1=x.b,*C1=x.C,*h1=x.h,*J1=x.J;
  const float *A2=y.A,*b2=y.b,*C2=y.C,*h2=y.h,*J2=y.J;
  FE o;
  float Mx[9]; mm(C1,J2,Mx); Mx[0]+=1.0f; Mx[4]+=1.0f; Mx[8]+=1.0f;
  float Mi[9]; inv3f(Mx,Mi);
  float T1[9]; mm(A2,Mi,T1);
  mm(T1,A1,o.A);
  float u[3]; mv(C1,h2,u); u[0]+=b1[0]; u[1]+=b1[1]; u[2]+=b1[2];
  mv(T1,u,o.b); o.b[0]+=b2[0]; o.b[1]+=b2[1]; o.b[2]+=b2[2];
  float t2[9]; mm(T1,C1,t2);
  mmnt(t2,A2,o.C);
#pragma unroll
  for (int i=0;i<9;++i) o.C[i]+=C2[i];
  float tmp[9]; mm(Mi,A1,tmp);
  float w[3]; mv(J2,b1,w);
  w[0]=h2[0]-w[0]; w[1]=h2[1]-w[1]; w[2]=h2[2]-w[2];
  mtv(tmp,w,o.h); o.h[0]+=h1[0]; o.h[1]+=h1[1]; o.h[2]+=h1[2];
  float V[9]; mm(J2,A1,V);
  mtn(tmp,V,o.J);
#pragma unroll
  for (int i=0;i<9;++i) o.J[i]+=J1[i];
  symm(o.C); symm(o.J);
  return o;
}
// apply element y (later) to a state (m,P): reduced compose (A1=0,h1=0,J1=0)
DEV void fapply(const FE& y, float* m, float* P) {
  float Mx[9]; mm(P, y.J, Mx); Mx[0]+=1.0f; Mx[4]+=1.0f; Mx[8]+=1.0f;
  float Mi[9]; inv3f(Mx, Mi);
  float T1[9]; mm(y.A, Mi, T1);
  float u[3]; mv(P, y.h, u); u[0]+=m[0]; u[1]+=m[1]; u[2]+=m[2];
  float mn[3]; mv(T1, u, mn);
  m[0]=mn[0]+y.b[0]; m[1]=mn[1]+y.b[1]; m[2]=mn[2]+y.b[2];
  float t2[9]; mm(T1, P, t2);
  float Pn[9]; mmnt(t2, y.A, Pn);
#pragma unroll
  for (int i=0;i<9;++i) P[i]=Pn[i]+y.C[i];
  symm(P);
}
// plain Kalman step (replay)
DEV void fstep(const Model& M, float dt, float obsf, float rf, float Rf_,
               float* m, float* P) {
  float A[9], Q[9]; make_AQ(M, dt, A, Q);
  float mp[3]; mv(A, m, mp);
  float W[9]; mmnt(P, A, W);      // P A^T
  float Pp[9]; mm(A, W, Pp);
#pragma unroll
  for (int i=0;i<9;++i) Pp[i]+=Q[i];
  float S = Pp[0] + Rf_;
  float f = (obsf > 0.5f) ? (1.0f/S) : 0.0f;
  float K0=Pp[0]*f, K1=Pp[3]*f, K2=Pp[6]*f;
  float v = rf - mp[0];
  m[0]=mp[0]+K0*v; m[1]=mp[1]+K1*v; m[2]=mp[2]+K2*v;
  P[0]=Pp[0]-S*K0*K0; P[1]=Pp[1]-S*K0*K1; P[2]=Pp[2]-S*K0*K2;
  P[3]=Pp[3]-S*K1*K0; P[4]=Pp[4]-S*K1*K1; P[5]=Pp[5]-S*K1*K2;
  P[6]=Pp[6]-S*K2*K0; P[7]=Pp[7]-S*K2*K1; P[8]=Pp[8]-S*K2*K2;
  symm(P);
}

// ---------------- smoother affine map: x_k = G x_{k+1} + c ; P_k = G P G^T + U ----------------
struct SE { float G[9]; float c[3]; float U[9]; };

DEV SE se_identity() {
  SE s;
#pragma unroll
  for (int i=0;i<9;++i){ s.G[i]=0.0f; s.U[i]=0.0f; }
  s.G[0]=s.G[4]=s.G[8]=1.0f;
  s.c[0]=s.c[1]=s.c[2]=0.0f;
  return s;
}
DEV void se_store(const SE& s, float* g) {   // contiguous packed-18
#pragma unroll
  for (int i=0;i<9;++i) g[i]=s.G[i];
  g[9]=s.c[0]; g[10]=s.c[1]; g[11]=s.c[2];
  g[12]=s.U[0]; g[13]=s.U[1]; g[14]=s.U[2]; g[15]=s.U[4]; g[16]=s.U[5]; g[17]=s.U[8];
}
DEV SE se_load(const float* g) {
  SE s;
#pragma unroll
  for (int i=0;i<9;++i) s.G[i]=g[i];
  s.c[0]=g[9]; s.c[1]=g[10]; s.c[2]=g[11];
  s.U[0]=g[12]; s.U[1]=g[13]; s.U[2]=g[14];
  s.U[3]=g[13]; s.U[4]=g[15]; s.U[5]=g[16];
  s.U[6]=g[14]; s.U[7]=g[16]; s.U[8]=g[17];
  return s;
}
DEV void se_storeT(const SE& s, float* g, int idx, int n) {  // component-major
#pragma unroll
  for (int i=0;i<9;++i) g[i*n+idx]=s.G[i];
#pragma unroll
  for (int i=0;i<3;++i) g[(9+i)*n+idx]=s.c[i];
  g[12*n+idx]=s.U[0]; g[13*n+idx]=s.U[1]; g[14*n+idx]=s.U[2];
  g[15*n+idx]=s.U[4]; g[16*n+idx]=s.U[5]; g[17*n+idx]=s.U[8];
}
DEV SE se_loadT(const float* g, int idx, int n) {
  SE s;
#pragma unroll
  for (int i=0;i<9;++i) s.G[i]=g[i*n+idx];
#pragma unroll
  for (int i=0;i<3;++i) s.c[i]=g[(9+i)*n+idx];
  float u0=g[12*n+idx], u1=g[13*n+idx], u2=g[14*n+idx],
        u4=g[15*n+idx], u5=g[16*n+idx], u8=g[17*n+idx];
  s.U[0]=u0; s.U[1]=u1; s.U[2]=u2;
  s.U[3]=u1; s.U[4]=u4; s.U[5]=u5;
  s.U[6]=u2; s.U[7]=u5; s.U[8]=u8;
  return s;
}
// wave shuffle of SE, packed 18 (U symmetric)
DEV SE se_shfl_down(const SE& s, int d) {
  SE o;
#pragma unroll
  for (int i=0;i<9;++i) o.G[i]=__shfl_down(s.G[i], d, 64);
#pragma unroll
  for (int i=0;i<3;++i) o.c[i]=__shfl_down(s.c[i], d, 64);
  float u0=__shfl_down(s.U[0],d,64), u1=__shfl_down(s.U[1],d,64), u2=__shfl_down(s.U[2],d,64),
        u4=__shfl_down(s.U[4],d,64), u5=__shfl_down(s.U[5],d,64), u8=__shfl_down(s.U[8],d,64);
  o.U[0]=u0; o.U[1]=u1; o.U[2]=u2; o.U[3]=u1; o.U[4]=u4; o.U[5]=u5;
  o.U[6]=u2; o.U[7]=u5; o.U[8]=u8;
  return o;
}
// x earlier in time (applied LAST, since smoother runs backward)
DEV SE scompose(const SE& x, const SE& y) {
  SE o;
  mm(x.G, y.G, o.G);
  float t[3]; mv(x.G, y.c, t);
  o.c[0]=t[0]+x.c[0]; o.c[1]=t[1]+x.c[1]; o.c[2]=t[2]+x.c[2];
  float T[9]; mm(x.G, y.U, T);
  mmnt(T, x.G, o.U);
#pragma unroll
  for (int i=0;i<9;++i) o.U[i]+=x.U[i];
  symm(o.U);
  return o;
}
DEV void sapply(const SE& s, float* m, float* P) {
  float t[3]; mv(s.G, m, t);
  float T[9]; mm(s.G, P, T);
  float Pn[9]; mmnt(T, s.G, Pn);
  m[0]=t[0]+s.c[0]; m[1]=t[1]+s.c[1]; m[2]=t[2]+s.c[2];
#pragma unroll
  for (int i=0;i<9;++i) P[i]=Pn[i]+s.U[i];
  symm(P);
}
// smoother element from filtered register state (m,P) at k, dt to k+1
DEV SE selem_from_state(const Model& M, const float* m, const float* P, float dtn) {
  SE s;
  float A[9], Q[9]; make_AQ(M, dtn, A, Q);
  float W[9]; mmnt(P, A, W);      // P A^T
  float Pp[9]; mm(A, W, Pp);
#pragma unroll
  for (int j=0;j<9;++j) Pp[j]+=Q[j];
  float Pi_[9]; inv3d(Pp, Pi_);    // ill-conditioned -> double cofactors
  mm(W, Pi_, s.G);                 // G = P A^T Pp^-1
  float mp[3]; mv(A, m, mp);
  float gm[3]; mv(s.G, mp, gm);
  s.c[0]=m[0]-gm[0]; s.c[1]=m[1]-gm[1]; s.c[2]=m[2]-gm[2];
  float GW[9]; mmnt(s.G, W, GW);   // G Pp G^T
#pragma unroll
  for (int j=0;j<9;++j) s.U[j]=P[j]-GW[j];
  symm(s.U);
  return s;
}

// ================= kernels =================
// pk[k] = {time, residual, R, is_obs}  (natural order)
__global__ void k_merge(const float* __restrict__ times, const float* __restrict__ tstar,
                        const float* __restrict__ n1, const float* __restrict__ n2,
                        const float* __restrict__ mcp,
                        float4* pk, int* oix) {
  int g = blockIdx.x*blockDim.x + threadIdx.x;
  if (g >= T_TOT) return;
  float mc = mcp[0];
  if (g < N_TRAIN) {
    int i = g;
    float t = times[i];
    int lo = 0, hi = M_TEST;                 // count tstar strictly < t
    while (lo < hi) { int mid=(lo+hi)>>1; if (tstar[mid] < t) lo=mid+1; else hi=mid; }
    int p = i + lo;
    float s2 = n2[i];
    pk[p] = make_float4(t, n1[i]/s2 - mc, 1.0f/s2, 1.0f);
    oix[p] = -1;
  } else {
    int j = g - N_TRAIN;
    float t = tstar[j];
    int lo = 0, hi = N_TRAIN;                // count times <= t (stable: train first)
    while (lo < hi) { int mid=(lo+hi)>>1; if (times[mid] <= t) lo=mid+1; else hi=mid; }
    int p = j + lo;
    pk[p] = make_float4(t, 0.f, 1.f, 0.f);
    oix[p] = j;
  }
}

// F1: one element per thread, 64-wide shuffle inclusive scan (packed-27 shuffles).
__global__ __launch_bounds__(TPB, 3) void k_f1(
    const float* varp, const float* ellp, const float4* __restrict__ pk,
    float* tIncl, float* blkAgg) {
  int l = threadIdx.x, b = blockIdx.x;
  int t = b*TPB + l;
  Model M = make_model(varp, ellp);
  float4 q = pk[t];
  float dt = (t == 0) ? 0.0f : (q.x - pk[t-1].x);
  FE run = build_felem(M, dt, q.w, q.y, q.z, t == 0);
  for (int d = 1; d < TPB; d <<= 1) {
    FE oth = fe_shfl_up(run, d);
    FE comp = fcompose(oth, run);
    if (l >= d) run = comp;
  }
  fe_storeT(run, tIncl, t, T_TOT);
  if (l == TPB-1) fe_storeT(run, blkAgg, b, NBLK);
}

// F2a: 48 blocks x 64; shuffle-scan 64 block aggregates each -> blkIncl2, group agg.
__global__ __launch_bounds__(TPB, 2) void k_f2a(const float* __restrict__ blkAgg,
                                                float* blkIncl2, float* grpAgg) {
  int l = threadIdx.x, gb = blockIdx.x;
  int b = gb*GRP + l;
  FE run = fe_loadT(blkAgg, b, NBLK);
  for (int d = 1; d < TPB; d <<= 1) {
    FE oth = fe_shfl_up(run, d);
    FE comp = fcompose(oth, run);
    if (l >= d) run = comp;
  }
  fe_storeT(run, blkIncl2, b, NBLK);
  if (l == GRP-1) fe_store27(run, grpAgg + gb*FE_P);
}

// F2b: one 64-thread block shuffle-scans the 48 group aggregates -> exclusive prefix.
__global__ __launch_bounds__(TPB, 2) void k_f2b(const float* __restrict__ grpAgg,
                                                float* grpPref) {
  int j = threadIdx.x;
  FE run = (j < NGRP) ? fe_load27(grpAgg + j*FE_P) : fe_identity();
  for (int d = 1; d < TPB; d <<= 1) {
    FE oth = fe_shfl_up(run, d);
    FE comp = fcompose(oth, run);
    if (j >= d) run = comp;
  }
  FE X = fe_shfl_up(run, 1);
  if (j < NGRP) {
    if (j == 0) X = fe_identity();
    fe_store27(X, grpPref + j*FE_P);
  }
}

// F3 (+fused s1): entry state (<=2 fapplys) + fstep + smoother element in regs +
// backward in-wave suffix scan; store row-0 (5 floats) + lane0 block aggregate.
__global__ __launch_bounds__(TPB, 3) void k_f3(
    const float* varp, const float* ellp, const float4* __restrict__ pk,
    const float* __restrict__ tIncl, const float* __restrict__ blkIncl2,
    const float* __restrict__ grpPref,
    float* out5, float* blkAggS, float* xT) {
  int l = threadIdx.x, b = blockIdx.x;
  int t = b*TPB + l;
  int g = b >> 6, lb = b & (GRP-1);
  Model M = make_model(varp, ellp);
  float m[3], P[9];
  if (t == 0) {
    m[0]=m[1]=m[2]=0.0f; pinf(M, P);
  } else if (g == 0 && lb == 0) {            // block 0: tIncl[t-1] is a state
    fe_loadT_state(tIncl, t-1, T_TOT, m, P);
  } else if (g == 0) {                        // group 0: blkIncl2[b-1] is a state
    fe_loadT_state(blkIncl2, b-1, NBLK, m, P);
    if (l > 0) { FE y = fe_loadT(tIncl, t-1, T_TOT); fapply(y, m, P); }
  } else {                                    // grpPref[g] is a state
    const float* gp = grpPref + g*FE_P;
    m[0]=gp[9]; m[1]=gp[10]; m[2]=gp[11];
    P[0]=gp[12]; P[1]=gp[13]; P[2]=gp[14];
    P[3]=gp[13]; P[4]=gp[15]; P[5]=gp[16];
    P[6]=gp[14]; P[7]=gp[16]; P[8]=gp[17];
    if (lb > 0) { FE y = fe_loadT(blkIncl2, b-1, NBLK); fapply(y, m, P); }
    if (l  > 0) { FE y = fe_loadT(tIncl,  t-1, T_TOT); fapply(y, m, P); }
  }
  float4 q = pk[t];
  float dt = (t == 0) ? 0.0f : (q.x - pk[t-1].x);
  fstep(M, dt, q.w, q.y, q.z, m, P);
  SE e;
  if (t < T_TOT-1) {
    float dtn = pk[t+1].x - q.x;
    e = selem_from_state(M, m, P, dtn);
  } else {
    e = se_identity();
    xT[0]=m[0]; xT[1]=m[1]; xT[2]=m[2];
    xT[3]=P[0]; xT[4]=P[1]; xT[5]=P[2];
    xT[6]=P[4]; xT[7]=P[5]; xT[8]=P[8];
  }
  // backward in-wave suffix scan: Macc[l] = e_l ∘ ... ∘ e_63
  SE Macc = e;
  for (int d = 1; d < TPB; d <<= 1) {
    SE oth = se_shfl_down(Macc, d);
    SE c = scompose(Macc, oth);
    if (l + d < TPB) Macc = c;
  }
  // row-0 of the map is all s3 needs for (m0, P00)
  out5[0*T_TOT+t] = Macc.G[0];
  out5[1*T_TOT+t] = Macc.G[1];
  out5[2*T_TOT+t] = Macc.G[2];
  out5[3*T_TOT+t] = Macc.c[0];
  out5[4*T_TOT+t] = Macc.U[0];
  if (l == 0) se_storeT(Macc, blkAggS, b, NBLK);
}

// S2a: 48 blocks x 64; shuffle backward scan of block aggregates -> blkSuf2, group agg.
__global__ __launch_bounds__(TPB, 2) void k_s2a(const float* __restrict__ blkAggS,
                                                float* blkSuf2, float* grpAggS) {
  int l = threadIdx.x, gb = blockIdx.x;
  int b = gb*GRP + l;
  SE run = se_loadT(blkAggS, b, NBLK);
  for (int d = 1; d < TPB; d <<= 1) {
    SE oth = se_shfl_down(run, d);
    SE comp = scompose(run, oth);
    if (l + d < TPB) run = comp;
  }
  se_storeT(run, blkSuf2, b, NBLK);
  if (l == 0) se_store(run, grpAggS + gb*18);
}

// S2b: one 64-thread block backward-scans 48 group aggregates -> gExit[g] =
// smoothed state at first index of group g+1 (last group: xT).
__global__ __launch_bounds__(TPB, 2) void k_s2b(const float* __restrict__ grpAggS,
                                                const float* __restrict__ xT,
                                                float* gExit) {
  int j = threadIdx.x;
  SE run = (j < NGRP) ? se_load(grpAggS + j*18) : se_identity();
  for (int d = 1; d < TPB; d <<= 1) {
    SE oth = se_shfl_down(run, d);
    SE comp = scompose(run, oth);
    if (j + d < TPB) run = comp;
  }
  SE Sx = se_shfl_down(run, 1);   // suffix of groups j+1..
  if (j < NGRP) {
    float m[3] = { xT[0], xT[1], xT[2] };
    float P[9] = { xT[3],xT[4],xT[5], xT[4],xT[6],xT[7], xT[5],xT[7],xT[8] };
    if (j < NGRP-1) sapply(Sx, m, P);
    st_state(m, P, gExit + j*9);
  }
}

// S3: gExit[g] -> (blkSuf2[b+1]) -> row0(Macc[t]); write output.
__global__ __launch_bounds__(256, 4) void k_s3(
    const float* mcp, const float* __restrict__ out5,
    const float* __restrict__ blkSuf2, const float* __restrict__ gExit,
    const int* __restrict__ oix, float* out) {
  int t = blockIdx.x*256 + threadIdx.x;
  int b = t >> 6;
  int g = b >> 6, lb = b & (GRP-1);
  float mc = mcp[0];
  float m[3], P[9];
  ld_state(gExit + g*9, m, P);
  if (lb < GRP-1) {                  // -> state at first index of block b+1
    SE s = se_loadT(blkSuf2, b+1, NBLK);
    sapply(s, m, P);
  }
  float g0 = out5[0*T_TOT+t], g1 = out5[1*T_TOT+t], g2 = out5[2*T_TOT+t];
  float c0 = out5[3*T_TOT+t], u00 = out5[4*T_TOT+t];
  float mm0 = g0*m[0] + g1*m[1] + g2*m[2] + c0;
  float q0 = g0*P[0] + g1*P[3] + g2*P[6];
  float q1 = g0*P[1] + g1*P[4] + g2*P[7];
  float q2 = g0*P[2] + g1*P[5] + g2*P[8];
  float v00 = q0*g0 + q1*g1 + q2*g2 + u00;
  int j = oix[t];
  if (j >= 0) { out[j] = mm0 + mc; out[M_TEST + j] = fmaxf(v00, 0.0f); }
}

extern "C" void kernel_launch(void* const* d_in, const int* in_sizes, int n_in,
                              void* d_out, int out_size, void* d_ws, size_t ws_size,
                              hipStream_t stream) {
  const float* times = (const float*)d_in[0];
  const float* tstar = (const float*)d_in[1];
  const float* n1    = (const float*)d_in[2];
  const float* n2    = (const float*)d_in[3];
  const float* varp  = (const float*)d_in[4];
  const float* ellp  = (const float*)d_in[5];
  const float* mcp   = (const float*)d_in[6];
  float* out = (float*)d_out;

  size_t off = 0;
  auto take = [&](size_t bytes) {
    char* p = (char*)d_ws + off;
    off += (bytes + 255) & ~(size_t)255;
    return (void*)p;
  };
  float4* pk     = (float4*)take(sizeof(float4) * T_TOT);
  int*    oix    = (int*)   take(sizeof(int)    * T_TOT);
  float*  tIncl  = (float*) take(sizeof(float)  * FE_P * T_TOT);
  float*  blkAgg = (float*) take(sizeof(float)  * FE_P * NBLK);
  float*  blkIncl2=(float*) take(sizeof(float)  * FE_P * NBLK);
  float*  grpAgg = (float*) take(sizeof(float)  * FE_P * NGRP);
  float*  grpPref= (float*) take(sizeof(float)  * FE_P * NGRP);
  float*  out5   = (float*) take(sizeof(float)  * 5  * T_TOT);
  float*  blkAggS= (float*) take(sizeof(float)  * 18 * NBLK);
  float*  blkSuf2= (float*) take(sizeof(float)  * 18 * NBLK);
  float*  grpAggS= (float*) take(sizeof(float)  * 18 * NGRP);
  float*  gExit  = (float*) take(sizeof(float)  * 9  * NGRP);
  float*  xT     = (float*) take(sizeof(float)  * 9);
  (void)ws_size; (void)in_sizes; (void)n_in; (void)out_size;

  k_merge<<<(T_TOT+255)/256, 256, 0, stream>>>(times, tstar, n1, n2, mcp, pk, oix);
  k_f1   <<<NBLK, TPB, 0, stream>>>(varp, ellp, pk, tIncl, blkAgg);
  k_f2a  <<<NGRP, TPB, 0, stream>>>(blkAgg, blkIncl2, grpAgg);
  k_f2b  <<<1, TPB, 0, stream>>>(grpAgg, grpPref);
  k_f3   <<<NBLK, TPB, 0, stream>>>(varp, ellp, pk, tIncl, blkIncl2, grpPref, out5, blkAggS, xT);
  k_s2a  <<<NGRP, TPB, 0, stream>>>(blkAggS, blkSuf2, grpAggS);
  k_s2b  <<<1, TPB, 0, stream>>>(grpAggS, xT, gExit);
  k_s3   <<<T_TOT/256, 256, 0, stream>>>(mcp, out5, blkSuf2, gExit, oix, out);
}